// Round 5
// baseline (1267.848 us; speedup 1.0000x reference)
//
#include <hip/hip_runtime.h>
#include <cstdint>
#include <cstddef>

// ---------- problem constants ----------
#define B_   4
#define S_   4096
#define D_   1024
#define H_   16
#define KH   64
#define M_   256
#define FF_  4096

// fp16 compute path (same MFMA rate as bf16, lower quantization error)
typedef _Float16 bf16_t;
typedef _Float16 bf16x8 __attribute__((ext_vector_type(8)));
typedef _Float16 bf16x4 __attribute__((ext_vector_type(4)));
typedef float    f32x4  __attribute__((ext_vector_type(4)));

#define MFMA16(a,b,c) __builtin_amdgcn_mfma_f32_16x16x32_f16((a),(b),(c),0,0,0)

static constexpr size_t BSDc = (size_t)B_*S_*D_;   // 16,777,216 elements

// ---------- async global->LDS, 16B per lane ----------
__device__ __forceinline__ void async_copy16(const void* gp, void* lp) {
  auto g = reinterpret_cast<const __attribute__((address_space(1))) void*>(
      reinterpret_cast<uintptr_t>(gp));
  auto l = reinterpret_cast<__attribute__((address_space(3))) void*>(
      reinterpret_cast<uintptr_t>(lp));
  __builtin_amdgcn_global_load_lds(g, l, 16, 0, 0);
}

// ---------- generic B^T GEMM core (XOR bank-swizzled LDS tiles) ----------
// 64B rows of 4x16B chunks; slot j of row r holds global chunk j^((r>>1)&3).
// Fragment reads then hit 2-way bank groups (free) instead of 8-way.
template<int BM,int BN,int WROWS,int WCOLS,int WTM,int WTN>
__device__ __forceinline__ void gemm_bt_core(
    const bf16_t* __restrict__ At, int lda,
    const bf16_t* __restrict__ Bt, int ldb,
    int Kd, char* sm, f32x4 (&acc)[WTM][WTN])
{
  constexpr int NT = WROWS*WCOLS*64;
  static_assert(WROWS*WTM*16 == BM && WCOLS*WTN*16 == BN, "tile mismatch");
  const int t    = threadIdx.x;
  const int lane = t & 63;
  const int w    = t >> 6;
  const int wrow = w / WCOLS, wcol = w % WCOLS;
  const int l15  = lane & 15, quad = lane >> 4;
  char* As = sm;
  char* Bs = sm + BM*64;

#pragma unroll
  for (int i=0;i<WTM;i++)
#pragma unroll
    for (int j=0;j<WTN;j++)
      acc[i][j] = f32x4{0.f,0.f,0.f,0.f};

  constexpr int CA = BM*4;
  static_assert(CA % NT == 0, "A staging must be whole issues");
  constexpr int AI    = CA / NT;
  constexpr int BFULL = (BN*4) / NT;
  constexpr int BREM  = (BN*4) % NT;

  for (int kk = 0; kk < Kd; kk += 32) {
    __syncthreads();
#pragma unroll
    for (int ii=0; ii<AI; ii++) {
      int c  = ii*NT + t;
      int cw = ii*NT + (t & ~63);
      int r  = c >> 2;
      int js = (c & 3) ^ ((r >> 1) & 3);         // swizzled source chunk
      async_copy16(At + (size_t)r*lda + kk + js*8, As + (size_t)cw*16);
    }
#pragma unroll
    for (int ii=0; ii<BFULL; ii++) {
      int c  = ii*NT + t;
      int cw = ii*NT + (t & ~63);
      int r  = c >> 2;
      int js = (c & 3) ^ ((r >> 1) & 3);
      async_copy16(Bt + (size_t)r*ldb + kk + js*8, Bs + (size_t)cw*16);
    }
    if constexpr (BREM != 0) {
      if (t < BREM) {
        int c  = BFULL*NT + t;
        int cw = BFULL*NT + (t & ~63);
        int r  = c >> 2;
        int js = (c & 3) ^ ((r >> 1) & 3);
        async_copy16(Bt + (size_t)r*ldb + kk + js*8, Bs + (size_t)cw*16);
      }
    }
    __syncthreads();

    bf16x8 af[WTM], bv[WTN];
#pragma unroll
    for (int mi=0; mi<WTM; mi++) {
      int row = wrow*(WTM*16) + mi*16 + l15;
      int sw  = quad ^ ((row >> 1) & 3);
      af[mi] = *(const bf16x8*)(As + row*64 + sw*16);
    }
#pragma unroll
    for (int nj=0; nj<WTN; nj++) {
      int rn = wcol*(WTN*16) + nj*16 + l15;
      int sw = quad ^ ((rn >> 1) & 3);
      bv[nj] = *(const bf16x8*)(Bs + rn*64 + sw*16);
    }
#pragma unroll
    for (int mi=0; mi<WTM; mi++)
#pragma unroll
      for (int nj=0; nj<WTN; nj++)
        acc[mi][nj] = MFMA16(af[mi], bv[nj], acc[mi][nj]);
  }
}

// ---------- epilogue variants ----------
enum { E_BF16 = 0, E_GELU = 2, E_RESF32 = 3, E_QKV = 5 };

// exact-GELU via A&S 7.1.26 erf approximation (|err| ~1.5e-7, far below the
// fp16 storage quantization of h1). Avoids the erff libcall (~2-3x VALU ops).
__device__ __forceinline__ float gelu_f(float v) {
  float u  = v * 0.70710678118654752f;
  float au = fabsf(u);
  float tt = __builtin_amdgcn_rcpf(1.0f + 0.3275911f*au);
  float poly = tt*(0.254829592f + tt*(-0.284496736f + tt*(1.421413741f +
               tt*(-1.453152027f + tt*1.061405429f))));
  float er = 1.0f - poly*__expf(-au*au);
  er = __builtin_copysignf(er, u);
  return 0.5f * v * (1.0f + er);
}

template<int BM,int BN,int WROWS,int WCOLS,int WTM,int WTN,int EPI>
__global__ __launch_bounds__(WROWS*WCOLS*64)
void gemm_bt_kernel(const bf16_t* __restrict__ A, int lda,
                    const bf16_t* __restrict__ Bt, int ldb,
                    void* __restrict__ C, int ldc,
                    int Kd, const float* __restrict__ bias, const float* __restrict__ res)
{
  extern __shared__ float4 smem4[];
  char* sm = (char*)smem4;

  // XCD-aware bijective swizzle (T1): hardware round-robins linear block id
  // across 8 XCDs; remap so each XCD owns a contiguous chunk of work ->
  // B-panel stays resident in that XCD's 4MB L2 (grids here are %8==0).
  const int nbx = gridDim.x;
  const int nwg = nbx * gridDim.y;
  int bx, by;
  {
    int orig = blockIdx.y * nbx + blockIdx.x;
    if ((nwg & 7) == 0) {
      int swz = (orig & 7) * (nwg >> 3) + (orig >> 3);
      bx = swz % nbx; by = swz / nbx;
    } else { bx = blockIdx.x; by = blockIdx.y; }
  }

  const bf16_t* At  = A  + (size_t)bx*BM*lda;
  const bf16_t* Bt2 = Bt + (size_t)by*BN*ldb;
  f32x4 acc[WTM][WTN];
  gemm_bt_core<BM,BN,WROWS,WCOLS,WTM,WTN>(At, lda, Bt2, ldb, Kd, sm, acc);

  const int t=threadIdx.x, lane=t&63, w=t>>6;
  const int wrow=w/WCOLS, wcol=w%WCOLS, l15=lane&15, quad=lane>>4;

  if constexpr (EPI == E_QKV) {
    // merged QKV: by 0..7 -> q, 8..15 -> k, 16..23 -> vT (transposed)
    const int yb = by;
    bf16_t* base = (bf16_t*)C;              // qb; kb = +BSD; vT = +2*BSD
    if (yb < 16) {
      bf16_t* dst = base + (size_t)(yb >> 3) * BSDc;
      const size_t colbase = (size_t)(yb & 7) * 128;
#pragma unroll
      for (int mi=0; mi<WTM; mi++)
#pragma unroll
        for (int nj=0; nj<WTN; nj++) {
          size_t col = colbase + wcol*64 + nj*16 + l15;
#pragma unroll
          for (int reg=0; reg<4; reg++) {
            size_t row = (size_t)bx*128 + wrow*64 + mi*16 + quad*4 + reg;
            dst[row*D_ + col] = (bf16_t)acc[mi][nj][reg];
          }
        }
    } else {
      bf16_t* vT = base + 2*BSDc;
      bf16_t* ldsT = (bf16_t*)sm;           // [64 cols][136 rows]
      const int b  = (bx*128) >> 12;
      const int s0 = (bx*128) & 4095;
#pragma unroll
      for (int half=0; half<2; half++) {
        __syncthreads();                    // core LDS reads done / prev drain done
        if (wcol == half) {
#pragma unroll
          for (int mi=0; mi<WTM; mi++)
#pragma unroll
            for (int nj=0; nj<WTN; nj++)
#pragma unroll
              for (int reg=0; reg<4; reg++) {
                int col = nj*16 + l15;
                int row = wrow*64 + mi*16 + quad*4 + reg;
                ldsT[col*136 + row] = (bf16_t)acc[mi][nj][reg];
              }
        }
        __syncthreads();
        // 64 cols x 16 chunks = 1024 -> 4 passes
#pragma unroll
        for (int pass=0; pass<4; pass++) {
          int idx = pass*256 + t;
          int col = idx >> 4, ch = idx & 15;
          int d = (yb-16)*128 + half*64 + col;
          int hh = d >> 6, cc = d & 63;
          bf16x8 v = *(const bf16x8*)(ldsT + col*136 + ch*8);
          *(bf16x8*)(vT + (((size_t)b*H_ + hh)*KH + cc)*S_ + s0 + ch*8) = v;
        }
      }
    }
    return;
  }

#pragma unroll
  for (int mi=0; mi<WTM; mi++) {
#pragma unroll
    for (int nj=0; nj<WTN; nj++) {
      size_t col = (size_t)by*BN + wcol*(WTN*16) + nj*16 + l15;
#pragma unroll
      for (int reg=0; reg<4; reg++) {
        size_t row = (size_t)bx*BM + wrow*(WTM*16) + mi*16 + quad*4 + reg;
        float v = acc[mi][nj][reg];
        if constexpr (EPI == E_BF16) {
          ((bf16_t*)C)[row*ldc + col] = (bf16_t)v;
        } else if constexpr (EPI == E_GELU) {
          v += bias[col];
          v = gelu_f(v);
          ((bf16_t*)C)[row*ldc + col] = (bf16_t)v;
        } else {  // E_RESF32
          if (bias) v += bias[col];
          v += res[row*(size_t)ldc + col];
          ((float*)C)[row*ldc + col] = v;
        }
      }
    }
  }
}

// ---------- fused phi(k) + kv aggregation ----------
// grid: (8 seg, 64 bh).  kvp fp32 [seg][bh][256 m][80 c]
// (no XCD swizzle: natural orig%8==g already groups one kb segment per XCD)
__global__ __launch_bounds__(256)
void kv_fused(const bf16_t* __restrict__ kb, const float* __restrict__ sqk,
              const bf16_t* __restrict__ omg, const bf16_t* __restrict__ vT,
              float* __restrict__ kvp)
{
  extern __shared__ float4 smem4[];
  char* sm = (char*)smem4;
  bf16_t* PT   = (bf16_t*)sm;             // [256 m][72] (overlaps core As/Bs)
  bf16_t* Vs   = (bf16_t*)(sm + 36864);   // [80 c][64 s] (128B rows, 8 chunks, swizzled)
  float*  stab = (float*)(sm + 47104);    // 256
  float*  comb = (float*)(sm + 48128);    // 64
  const int g = blockIdx.x, bh = blockIdx.y, b = bh >> 4, h = bh & 15;
  const int t=threadIdx.x, lane=t&63, w=t>>6, l15=lane&15, quad=lane>>4;
  const float scale = 0.35355339059327379f;   // 64^-0.25

  // constant Vs rows: 64 = ones (z), 65..79 = zeros (uniform per row: swizzle-safe)
#pragma unroll
  for (int j=0;j<4;j++){
    int idx = j*256 + t;
    int r = 64 + (idx>>6), s = idx & 63;
    Vs[r*64 + s] = (bf16_t)((r==64) ? 1.0f : 0.0f);
  }

  f32x4 acc2[4][5];
#pragma unroll
  for (int i=0;i<4;i++)
#pragma unroll
    for (int j=0;j<5;j++) acc2[i][j] = f32x4{0.f,0.f,0.f,0.f};

  for (int ch=0; ch<8; ch++) {
    const int s0 = g*512 + ch*64;
    const bf16_t* At = kb + ((size_t)b*S_ + s0)*D_ + h*KH;
    f32x4 acc[4][4];
    gemm_bt_core<64,256,1,4,4,4>(At, D_, omg, KH, KH, sm, acc);

#pragma unroll
    for (int mi=0; mi<4; mi++) {
#pragma unroll
      for (int reg=0; reg<4; reg++) {
        float mx = fmaxf(fmaxf(acc[mi][0][reg], acc[mi][1][reg]),
                         fmaxf(acc[mi][2][reg], acc[mi][3][reg]));
#pragma unroll
        for (int off=1; off<16; off<<=1) mx = fmaxf(mx, __shfl_xor(mx, off, 64));
        if (l15 == 0) stab[w*64 + mi*16 + quad*4 + reg] = mx;
      }
    }
    __syncthreads();
    if (t < 64) {
      float m4 = fmaxf(fmaxf(stab[t], stab[64+t]), fmaxf(stab[128+t], stab[192+t]));
      comb[t] = m4*scale + sqk[(size_t)bh*S_ + s0 + t];
    }
    __syncthreads();
    // PT[m][s] = phi  (transposed write; stride 72 elem = 144B, bank-rotating)
#pragma unroll
    for (int mi=0; mi<4; mi++)
#pragma unroll
      for (int nj=0; nj<4; nj++)
#pragma unroll
        for (int reg=0; reg<4; reg++) {
          int row = mi*16 + quad*4 + reg;          // s-local
          int col = w*64 + nj*16 + l15;            // m
          float p = __expf(scale*acc[mi][nj][reg] - comb[row]) * 0.0625f + 1e-6f;
          PT[col*72 + row] = (bf16_t)p;
        }
    // stage Vs rows 0..63 from vT, chunk-swizzled: slot j holds chunk j^(r&7)
#pragma unroll
    for (int ii=0; ii<2; ii++) {
      int c2 = ii*256 + t;
      int cw = ii*256 + (t & ~63);
      int r  = c2 >> 3;
      int js = (c2 & 7) ^ (r & 7);
      async_copy16(vT + ((size_t)bh*KH + r)*S_ + s0 + js*8,
                   (char*)Vs + (size_t)cw*16);
    }
    __syncthreads();
    // phase B: kv[m][c] += sum_s PT[m][s] * Vs[c][s]
#pragma unroll
    for (int ks=0; ks<2; ks++) {
      bf16x8 af[4];
#pragma unroll
      for (int mi=0; mi<4; mi++)
        af[mi] = *(const bf16x8*)(PT + (w*64 + mi*16 + l15)*72 + ks*32 + quad*8);
#pragma unroll
      for (int nj=0; nj<5; nj++) {
        int rr = nj*16 + l15;
        int slot = (ks*4 + quad) ^ (rr & 7);
        bf16x8 bv = *(const bf16x8*)(Vs + rr*64 + slot*8);
#pragma unroll
        for (int mi=0; mi<4; mi++)
          acc2[mi][nj] = MFMA16(af[mi], bv, acc2[mi][nj]);
      }
    }
  }

#pragma unroll
  for (int mi=0; mi<4; mi++)
#pragma unroll
    for (int nj=0; nj<5; nj++)
#pragma unroll
      for (int reg=0; reg<4; reg++) {
        int m = w*64 + mi*16 + quad*4 + reg;
        int c = nj*16 + l15;
        kvp[(((size_t)g*64 + bh)*256 + m)*80 + c] = acc2[mi][nj][reg];
      }
}

// reduce 8 segments -> kvT[bh][c][m] fp16; grid (4 mblk, 64 bh)
// Coalesced rewrite: old version read kvp at stride 320B/lane (16x overfetch).
// Now: linear coalesced reads (kvp[m][c] is contiguous), register accumulate
// over segments, LDS transpose (stride 81 -> <=2-way banks), 128B fp16 writes.
__global__ __launch_bounds__(256)
void kvred_kernel(const float* __restrict__ kvp, bf16_t* __restrict__ kvT)
{
  __shared__ float accs[64*81];
  const int mb = blockIdx.x, bh = blockIdx.y, t = threadIdx.x;
  const int m0 = mb*64;
  float r[20];
#pragma unroll
  for (int i=0;i<20;i++) r[i] = 0.f;
  for (int g2=0; g2<8; g2++) {
    const float* p = kvp + (((size_t)g2*64 + bh)*256 + m0)*80;
#pragma unroll
    for (int i=0;i<20;i++) r[i] += p[i*256 + t];
  }
#pragma unroll
  for (int i=0;i<20;i++) {
    int idx = i*256 + t;           // = mloc*80 + c
    int ml = idx / 80, cc = idx - ml*80;
    accs[ml*81 + cc] = r[i];
  }
  __syncthreads();
  bf16_t* o = kvT + (size_t)bh*(80*M_);
#pragma unroll
  for (int i=0;i<20;i++) {
    int idx2 = i*256 + t;          // = c*64 + mloc
    int c = idx2 >> 6, ml = idx2 & 63;
    o[(size_t)c*M_ + m0 + ml] = (bf16_t)accs[ml*81 + c];
  }
}

// ---------- fused phi(q) + num/den ----------
// grid: (S/64, B*H).  attn written in-place over qb.
// (no XCD swizzle: orig%8 == sx%8 already co-locates same-row h-groups)
__global__ __launch_bounds__(256)
void numden_fused(const bf16_t* __restrict__ qb, const float* __restrict__ sqv,
                  const bf16_t* __restrict__ omg, const bf16_t* __restrict__ kvT,
                  bf16_t* __restrict__ attn)
{
  extern __shared__ float4 smem4[];
  char* sm = (char*)smem4;
  bf16_t* P    = (bf16_t*)sm;             // [64 s][264 m] (overlaps core As/Bs)
  char*   Bs2  = sm + 33792;              // 80 rows x 64B (4 chunks, swizzled)
  float*  stab = (float*)(sm + 38912);
  float*  comb = (float*)(sm + 39936);
  const int bh = blockIdx.y, b = bh >> 4, h = bh & 15;
  const int s0 = blockIdx.x * 64;
  const bf16_t* At = qb + ((size_t)b*S_ + s0)*D_ + h*KH;
  f32x4 acc[4][4];
  gemm_bt_core<64,256,1,4,4,4>(At, D_, omg, KH, KH, sm, acc);

  const int t=threadIdx.x, lane=t&63, w=t>>6, l15=lane&15, quad=lane>>4;
  const float scale = 0.35355339059327379f;

#pragma unroll
  for (int mi=0; mi<4; mi++) {
#pragma unroll
    for (int reg=0; reg<4; reg++) {
      float mx = fmaxf(fmaxf(acc[mi][0][reg], acc[mi][1][reg]),
                       fmaxf(acc[mi][2][reg], acc[mi][3][reg]));
#pragma unroll
      for (int off=1; off<16; off<<=1) mx = fmaxf(mx, __shfl_xor(mx, off, 64));
      if (l15 == 0) stab[w*64 + mi*16 + quad*4 + reg] = mx;
    }
  }
  __syncthreads();
  if (t < 64) {
    float m4 = fmaxf(fmaxf(stab[t], stab[64+t]), fmaxf(stab[128+t], stab[192+t]));
    comb[t] = m4*scale + sqv[(size_t)bh*S_ + s0 + t];
  }
  __syncthreads();
#pragma unroll
  for (int mi=0; mi<4; mi++)
#pragma unroll
    for (int nj=0; nj<4; nj++)
#pragma unroll
      for (int reg=0; reg<4; reg++) {
        int row = mi*16 + quad*4 + reg;
        int col = w*64 + nj*16 + l15;
        float p = __expf(scale*acc[mi][nj][reg] - comb[row]) * 0.0625f + 1e-6f;
        P[row*264 + col] = (bf16_t)p;
      }

  // phase B: [64 x 80] = P[64x256] x kvT[80x256]^T
  const bf16_t* Bt = kvT + (size_t)bh*80*M_;
  f32x4 acc2[5];
#pragma unroll
  for (int j=0;j<5;j++) acc2[j] = f32x4{0.f,0.f,0.f,0.f};

  for (int kk = 0; kk < 256; kk += 32) {
    __syncthreads();                       // P visible (1st it) / Bs2 reads done
    {
      int c = t, cw = (t & ~63);
      int r = c >> 2;
      int js = (c & 3) ^ ((r >> 1) & 3);
      async_copy16(Bt + (size_t)r*M_ + kk + js*8, Bs2 + (size_t)cw*16);
    }
    if (t < 64) {                          // rows 64..79 (wave 0)
      int c = 256 + t;
      int r = c >> 2;
      int js = (c & 3) ^ ((r >> 1) & 3);
      async_copy16(Bt + (size_t)r*M_ + kk + js*8, Bs2 + (size_t)256*16);
    }
    __syncthreads();
    bf16x8 af = *(const bf16x8*)(P + (w*16 + l15)*264 + kk + quad*8);
#pragma unroll
    for (int nj=0; nj<5; nj++) {
      int rn = nj*16 + l15;
      int sw = quad ^ ((rn >> 1) & 3);
      bf16x8 bv = *(const bf16x8*)(Bs2 + rn*64 + sw*16);
      acc2[nj] = MFMA16(af, bv, acc2[nj]);
    }
  }

#pragma unroll
  for (int reg=0; reg<4; reg++) {
    float den = __shfl(acc2[4][reg], (lane & 48), 64);
    int row = w*16 + quad*4 + reg;
#pragma unroll
    for (int nj=0; nj<4; nj++) {
      float v = acc2[nj][reg] / den;
      attn[((size_t)b*S_ + s0 + row)*D_ + h*KH + nj*16 + l15] = (bf16_t)v;
    }
  }
}

// ---------- small kernels ----------
__global__ __launch_bounds__(256)
void cvt_kernel(const float* __restrict__ in, bf16_t* __restrict__ out)
{
  const size_t i = ((size_t)blockIdx.x*256 + threadIdx.x)*4;
  const float4 a = *(const float4*)(in + i);
  bf16x4 o; o[0]=(bf16_t)a.x; o[1]=(bf16_t)a.y; o[2]=(bf16_t)a.z; o[3]=(bf16_t)a.w;
  *(bf16x4*)(out + i) = o;
}

// transpose fp32 [R][C] -> fp16 [C][R]; grid (C/64, R/64)
__global__ __launch_bounds__(256)
void tcvt_kernel(const float* __restrict__ in, bf16_t* __restrict__ out, int R, int C)
{
  __shared__ float tile[64][65];
  const int r0 = blockIdx.y*64, c0 = blockIdx.x*64;
  const int tx = threadIdx.x & 63, ty = threadIdx.x >> 6;
  for (int i=ty; i<64; i+=4) tile[i][tx] = in[(size_t)(r0+i)*C + c0 + tx];
  __syncthreads();
  for (int i=ty; i<64; i+=4) out[(size_t)(c0+i)*R + r0 + tx] = (bf16_t)tile[tx][i];
}

// merged wq/wk/wv transpose (1024x1024 each) -> stacked wqkvT; grid (16, 48)
__global__ __launch_bounds__(256)
void tcvt3_kernel(const float* __restrict__ wqp, const float* __restrict__ wkp,
                  const float* __restrict__ wvp, bf16_t* __restrict__ out)
{
  __shared__ float tile[64][65];
  const int sel = blockIdx.y >> 4, ry = blockIdx.y & 15;
  const float* in = (sel==0) ? wqp : (sel==1) ? wkp : wvp;
  bf16_t* o = out + (size_t)sel*D_*D_;
  const int r0 = ry*64, c0 = blockIdx.x*64;
  const int tx = threadIdx.x & 63, ty = threadIdx.x >> 6;
  for (int i=ty; i<64; i+=4) tile[i][tx] = in[(size_t)(r0+i)*D_ + c0 + tx];
  __syncthreads();
  for (int i=ty; i<64; i+=4) o[(size_t)(c0+i)*D_ + r0 + tx] = (bf16_t)tile[tx][i];
}

// merged sq for q and k: blocks 0..4095 -> qb rows, 4096..8191 -> kb rows
// sq[b,h,s] = 0.0625 * sum over head's 64 dims of row^2
__global__ __launch_bounds__(256)
void sq2_kernel(const bf16_t* __restrict__ qkv, float* __restrict__ sqq,
                float* __restrict__ sqk)
{
  const int bi   = blockIdx.x;
  const int ksel = bi >> 12;
  const int i    = ((bi & 4095)<<2) + (threadIdx.x>>6);
  const int lane = threadIdx.x & 63;
  const bf16_t* row = qkv + (size_t)ksel*BSDc + (size_t)i*D_ + lane*16;
  bf16x8 v0 = *(const bf16x8*)row;
  bf16x8 v1 = *(const bf16x8*)(row + 8);
  float s = 0.f;
#pragma unroll
  for (int j=0;j<8;j++){ float a=(float)v0[j], c=(float)v1[j]; s += a*a + c*c; }
  s += __shfl_xor(s, 1, 64);
  s += __shfl_xor(s, 2, 64);
  if ((lane&3)==0) {
    const int h = lane>>2, b = i>>12, ss = i & 4095;
    float* sq = ksel ? sqk : sqq;
    sq[((size_t)b*H_ + h)*S_ + ss] = 0.0625f * s;
  }
}

// layernorm over 1024 cols; one block per row; optional fp16 copy
template<bool WB>
__global__ __launch_bounds__(256)
void ln_kernel(const float* __restrict__ in, const float* __restrict__ g,
               const float* __restrict__ bt, float* __restrict__ outf,
               bf16_t* __restrict__ outb)
{
  __shared__ float rs[4], rs2[4];
  const size_t row = blockIdx.x;
  const int t = threadIdx.x;
  const float4 a = ((const float4*)(in + row*D_))[t];
  float s  = a.x+a.y+a.z+a.w;
  float s2 = a.x*a.x + a.y*a.y + a.z*a.z + a.w*a.w;
#pragma unroll
  for (int off=32; off; off>>=1) { s += __shfl_xor(s, off, 64); s2 += __shfl_xor(s2, off, 64); }
  if ((t&63)==0) { rs[t>>6]=s; rs2[t>>6]=s2; }
  __syncthreads();
  const float S1 = rs[0]+rs[1]+rs[2]+rs[3];
  const float S2 = rs2[0]+rs2[1]+rs2[2]+rs2[3];
  const float mu   = S1 * (1.f/1024.f);
  const float rstd = rsqrtf(S2 * (1.f/1024.f) - mu*mu + 1e-6f);
  const float4 gg = ((const float4*)g)[t];
  const float4 bb = ((const float4*)bt)[t];
  float4 oo;
  oo.x = (a.x-mu)*rstd*gg.x + bb.x;
  oo.y = (a.y-mu)*rstd*gg.y + bb.y;
  oo.z = (a.z-mu)*rstd*gg.z + bb.z;
  oo.w = (a.w-mu)*rstd*gg.w + bb.w;
  ((float4*)(outf + row*D_))[t] = oo;
  if constexpr (WB) {
    bf16x4 ob; ob[0]=(bf16_t)oo.x; ob[1]=(bf16_t)oo.y; ob[2]=(bf16_t)oo.z; ob[3]=(bf16_t)oo.w;
    *(bf16x4*)(outb + row*D_ + t*4) = ob;
  }
}

// ---------- load-time fallback workspace ----------
static const size_t NEED = 420000000;   // > actual ~391 MB usage
static void* g_fb = nullptr;
struct FbInit {
  FbInit() { if (hipMalloc(&g_fb, NEED) != hipSuccess) g_fb = nullptr; }
};
static FbInit g_fbinit;

// ---------- launcher ----------
extern "C" void kernel_launch(void* const* d_in, const int* in_sizes, int n_in,
                              void* d_out, int out_size, void* d_ws, size_t ws_size,
                              hipStream_t stream)
{
  (void)in_sizes; (void)n_in; (void)out_size;
  const float* x     = (const float*)d_in[0];
  const float* wq    = (const float*)d_in[1];
  const float* wk    = (const float*)d_in[2];
  const float* wv    = (const float*)d_in[3];
  const float* wo    = (const float*)d_in[4];
  const float* omega = (const float*)d_in[5];
  const float* ln1g  = (const float*)d_in[6];
  const float* ln1b  = (const float*)d_in[7];
  const float* w1    = (const float*)d_in[8];
  const float* b1    = (const float*)d_in[9];
  const float* w2    = (const float*)d_in[10];
  const float* b2    = (const float*)d_in[11];
  const float* ln2g  = (const float*)d_in[12];
  const float* ln2b  = (const float*)d_in[13];
  float* out = (float*)d_out;

  char* ws = (ws_size >= NEED) ? (char*)d_ws : (char*)g_fb;
  if (!ws) return;

  size_t o = 0;
  auto alloc = [&](size_t bytes) -> char* {
    char* p = ws + o; o += (bytes + 255) & ~(size_t)255; return p;
  };
  const size_t BSD = BSDc;

  bf16_t* wqkvT = (bf16_t*)alloc((size_t)3*D_*D_*2);      // stacked q|k|v B^T
  bf16_t* woT   = (bf16_t*)alloc((size_t)D_*D_*2);
  bf16_t* w1T   = (bf16_t*)alloc((size_t)D_*FF_*2);
  bf16_t* w2T   = (bf16_t*)alloc((size_t)D_*FF_*2);
  bf16_t* omg   = (bf16_t*)alloc((size_t)M_*KH*2);
  float*  sqq   = (float*)alloc((size_t)B_*H_*S_*4);
  float*  sqk   = (float*)alloc((size_t)B_*H_*S_*4);
  bf16_t* kvT   = (bf16_t*)alloc((size_t)B_*H_*80*M_*2);
  float*  kvp   = (float*)alloc((size_t)8*64*256*80*4);   // 42 MB

  bf16_t* xb    = (bf16_t*)alloc(BSD*2);                  // -> x1b
  bf16_t* qkv   = (bf16_t*)alloc(3*BSD*2);                // qb | kb | vT contiguous
  bf16_t* h1    = (bf16_t*)alloc(BSD*4*2);                // 128 MB fp16 [16384][4096]
  float*  y2    = (float*)alloc(BSD*4);                   // 64 MB fp32

  bf16_t* x1b  = xb;
  bf16_t* qb   = qkv;
  bf16_t* kb   = qkv + BSD;
  bf16_t* vT   = qkv + 2*BSD;
  bf16_t* attn = qb;              // in-place over qb
  float*  y1   = (float*)d_out;   // fp32 [16384,1024] lives in d_out until LN2

  constexpr int SH128 = (128+128)*64;      // 16384
  constexpr int SHQKV = 64*136*2;          // 17408 (>= core 16384)
  constexpr int SHKF  = 48384;
  constexpr int SHND  = 40192;

  // 1. converts / weight transposes
  cvt_kernel<<<(int)(BSD/1024), 256, 0, stream>>>(x, xb);
  tcvt3_kernel<<<dim3(16,48), 256, 0, stream>>>(wq, wk, wv, wqkvT);
  tcvt_kernel<<<dim3(16,16), 256, 0, stream>>>(wo, woT, 1024, 1024);
  tcvt_kernel<<<dim3(64,16), 256, 0, stream>>>(w1, w1T, 1024, 4096);
  tcvt_kernel<<<dim3(16,64), 256, 0, stream>>>(w2, w2T, 4096, 1024);
  cvt_kernel<<<16, 256, 0, stream>>>(omega, omg);

  // 2. merged QKV projection: [16384,1024] x [3072,1024]^T, 3072 blocks
  gemm_bt_kernel<128,128,2,2,4,4,E_QKV><<<dim3(128,24), 256, SHQKV, stream>>>(
      xb, D_, wqkvT, D_, qkv, D_, D_, nullptr, nullptr);

  // 3. sq (merged q+k)
  sq2_kernel<<<8192, 256, 0, stream>>>(qkv, sqq, sqk);

  // 4. fused phi(k)+kv aggregation (8 segments = 512 blocks), then reduce
  kv_fused<<<dim3(8,64), 256, SHKF, stream>>>(kb, sqk, omg, vT, kvp);
  kvred_kernel<<<dim3(4,64), 256, 0, stream>>>(kvp, kvT);

  // 5. fused phi(q)+num/den -> attn (in place over qb)
  numden_fused<<<dim3(64,64), 256, SHND, stream>>>(qb, sqq, omg, kvT, attn);

  // 6. out projection + residual(x) -> y1 (in d_out); LN1 in-place + fp16 copy
  gemm_bt_kernel<128,128,2,2,4,4,E_RESF32><<<dim3(128,8), 256, SH128, stream>>>(
      attn, D_, woT, D_, y1, D_, D_, nullptr, x);
  ln_kernel<true><<<B_*S_, 256, 0, stream>>>(y1, ln1g, ln1b, y1, x1b);

  // 7. FFN, full size (FFN1: 4096 blocks; FFN2: 1024 blocks, K=4096)
  gemm_bt_kernel<128,128,2,2,4,4,E_GELU><<<dim3(128,32), 256, SH128, stream>>>(
      x1b, D_, w1T, D_, h1, FF_, D_, b1, nullptr);
  gemm_bt_kernel<128,128,2,2,4,4,E_RESF32><<<dim3(128,8), 256, SH128, stream>>>(
      h1, FF_, w2T, FF_, y2, D_, FF_, b2, y1);

  // 8. LN2 -> output
  ln_kernel<false><<<B_*S_, 256, 0, stream>>>(y2, ln2g, ln2b, out, nullptr);
}

// Round 9
// 1133.062 us; speedup vs baseline: 1.1190x; 1.1190x over previous
//
#include <hip/hip_runtime.h>
#include <cstdint>
#include <cstddef>

// ---------- problem constants ----------
#define B_   4
#define S_   4096
#define D_   1024
#define H_   16
#define KH   64
#define M_   256
#define FF_  4096

// fp16 compute path (same MFMA rate as bf16, lower quantization error)
typedef _Float16 bf16_t;
typedef _Float16 bf16x8 __attribute__((ext_vector_type(8)));
typedef _Float16 bf16x4 __attribute__((ext_vector_type(4)));
typedef float    f32x4  __attribute__((ext_vector_type(4)));

#define MFMA16(a,b,c) __builtin_amdgcn_mfma_f32_16x16x32_f16((a),(b),(c),0,0,0)

static constexpr size_t BSDc = (size_t)B_*S_*D_;   // 16,777,216 elements

// ---------- async global->LDS, 16B per lane ----------
__device__ __forceinline__ void async_copy16(const void* gp, void* lp) {
  auto g = reinterpret_cast<const __attribute__((address_space(1))) void*>(
      reinterpret_cast<uintptr_t>(gp));
  auto l = reinterpret_cast<__attribute__((address_space(3))) void*>(
      reinterpret_cast<uintptr_t>(lp));
  __builtin_amdgcn_global_load_lds(g, l, 16, 0, 0);
}

// ---------- generic B^T GEMM core (XOR bank-swizzled LDS tiles) ----------
template<int BM,int BN,int WROWS,int WCOLS,int WTM,int WTN>
__device__ __forceinline__ void gemm_bt_core(
    const bf16_t* __restrict__ At, int lda,
    const bf16_t* __restrict__ Bt, int ldb,
    int Kd, char* sm, f32x4 (&acc)[WTM][WTN])
{
  constexpr int NT = WROWS*WCOLS*64;
  static_assert(WROWS*WTM*16 == BM && WCOLS*WTN*16 == BN, "tile mismatch");
  const int t    = threadIdx.x;
  const int lane = t & 63;
  const int w    = t >> 6;
  const int wrow = w / WCOLS, wcol = w % WCOLS;
  const int l15  = lane & 15, quad = lane >> 4;
  char* As = sm;
  char* Bs = sm + BM*64;

#pragma unroll
  for (int i=0;i<WTM;i++)
#pragma unroll
    for (int j=0;j<WTN;j++)
      acc[i][j] = f32x4{0.f,0.f,0.f,0.f};

  constexpr int CA = BM*4;
  static_assert(CA % NT == 0, "A staging must be whole issues");
  constexpr int AI    = CA / NT;
  constexpr int BFULL = (BN*4) / NT;
  constexpr int BREM  = (BN*4) % NT;

  for (int kk = 0; kk < Kd; kk += 32) {
    __syncthreads();
#pragma unroll
    for (int ii=0; ii<AI; ii++) {
      int c  = ii*NT + t;
      int cw = ii*NT + (t & ~63);
      int r  = c >> 2;
      int js = (c & 3) ^ ((r >> 1) & 3);         // swizzled source chunk
      async_copy16(At + (size_t)r*lda + kk + js*8, As + (size_t)cw*16);
    }
#pragma unroll
    for (int ii=0; ii<BFULL; ii++) {
      int c  = ii*NT + t;
      int cw = ii*NT + (t & ~63);
      int r  = c >> 2;
      int js = (c & 3) ^ ((r >> 1) & 3);
      async_copy16(Bt + (size_t)r*ldb + kk + js*8, Bs + (size_t)cw*16);
    }
    if constexpr (BREM != 0) {
      if (t < BREM) {
        int c  = BFULL*NT + t;
        int cw = BFULL*NT + (t & ~63);
        int r  = c >> 2;
        int js = (c & 3) ^ ((r >> 1) & 3);
        async_copy16(Bt + (size_t)r*ldb + kk + js*8, Bs + (size_t)cw*16);
      }
    }
    __syncthreads();

    bf16x8 af[WTM], bv[WTN];
#pragma unroll
    for (int mi=0; mi<WTM; mi++) {
      int row = wrow*(WTM*16) + mi*16 + l15;
      int sw  = quad ^ ((row >> 1) & 3);
      af[mi] = *(const bf16x8*)(As + row*64 + sw*16);
    }
#pragma unroll
    for (int nj=0; nj<WTN; nj++) {
      int rn = wcol*(WTN*16) + nj*16 + l15;
      int sw = quad ^ ((rn >> 1) & 3);
      bv[nj] = *(const bf16x8*)(Bs + rn*64 + sw*16);
    }
#pragma unroll
    for (int mi=0; mi<WTM; mi++)
#pragma unroll
      for (int nj=0; nj<WTN; nj++)
        acc[mi][nj] = MFMA16(af[mi], bv[nj], acc[mi][nj]);
  }
}

// ---------- epilogue variants ----------
enum { E_BF16 = 0, E_GELU = 2, E_RESF32 = 3, E_QKV = 5, E_F32 = 6 };

// exact-GELU via A&S 7.1.26 erf approximation (|err| ~1.5e-7).
__device__ __forceinline__ float gelu_f(float v) {
  float u  = v * 0.70710678118654752f;
  float au = fabsf(u);
  float tt = __builtin_amdgcn_rcpf(1.0f + 0.3275911f*au);
  float poly = tt*(0.254829592f + tt*(-0.284496736f + tt*(1.421413741f +
               tt*(-1.453152027f + tt*1.061405429f))));
  float er = 1.0f - poly*__expf(-au*au);
  er = __builtin_copysignf(er, u);
  return 0.5f * v * (1.0f + er);
}

template<int BM,int BN,int WROWS,int WCOLS,int WTM,int WTN,int EPI>
__global__ __launch_bounds__(WROWS*WCOLS*64)
void gemm_bt_kernel(const bf16_t* __restrict__ A, int lda,
                    const bf16_t* __restrict__ Bt, int ldb,
                    void* __restrict__ C, int ldc,
                    int Kd, const float* __restrict__ bias, const float* __restrict__ res)
{
  extern __shared__ float4 smem4[];
  char* sm = (char*)smem4;

  // XCD-aware bijective swizzle (T1): each XCD owns a contiguous work chunk ->
  // its B-panel stays resident in that XCD's 4MB L2 (grids here are %8==0).
  const int nbx = gridDim.x;
  const int nwg = nbx * gridDim.y;
  int bx, by;
  {
    int orig = blockIdx.y * nbx + blockIdx.x;
    if ((nwg & 7) == 0) {
      int swz = (orig & 7) * (nwg >> 3) + (orig >> 3);
      bx = swz % nbx; by = swz / nbx;
    } else { bx = blockIdx.x; by = blockIdx.y; }
  }

  // E_F32 = split-K partials: by>>3 selects K-segment, by&7 the N-panel.
  int seg = 0;
  if constexpr (EPI == E_F32) { seg = by >> 3; by &= 7; }
  const int koff = seg * Kd;

  const bf16_t* At  = A  + (size_t)bx*BM*lda + koff;
  const bf16_t* Bt2 = Bt + (size_t)by*BN*ldb + koff;
  f32x4 acc[WTM][WTN];
  gemm_bt_core<BM,BN,WROWS,WCOLS,WTM,WTN>(At, lda, Bt2, ldb, Kd, sm, acc);

  const int t=threadIdx.x, lane=t&63, w=t>>6;
  const int wrow=w/WCOLS, wcol=w%WCOLS, l15=lane&15, quad=lane>>4;

  if constexpr (EPI == E_QKV) {
    // merged QKV: by 0..7 -> q, 8..15 -> k, 16..23 -> vT (transposed)
    const int yb = by;
    bf16_t* base = (bf16_t*)C;              // qb; kb = +BSD; vT = +2*BSD
    if (yb < 16) {
      bf16_t* dst = base + (size_t)(yb >> 3) * BSDc;
      const size_t colbase = (size_t)(yb & 7) * 128;
#pragma unroll
      for (int mi=0; mi<WTM; mi++)
#pragma unroll
        for (int nj=0; nj<WTN; nj++) {
          size_t col = colbase + wcol*64 + nj*16 + l15;
#pragma unroll
          for (int reg=0; reg<4; reg++) {
            size_t row = (size_t)bx*128 + wrow*64 + mi*16 + quad*4 + reg;
            dst[row*D_ + col] = (bf16_t)acc[mi][nj][reg];
          }
        }
    } else {
      bf16_t* vT = base + 2*BSDc;
      bf16_t* ldsT = (bf16_t*)sm;           // [64 cols][136 rows]
      const int b  = (bx*128) >> 12;
      const int s0 = (bx*128) & 4095;
#pragma unroll
      for (int half=0; half<2; half++) {
        __syncthreads();                    // core LDS reads done / prev drain done
        if (wcol == half) {
#pragma unroll
          for (int mi=0; mi<WTM; mi++)
#pragma unroll
            for (int nj=0; nj<WTN; nj++)
#pragma unroll
              for (int reg=0; reg<4; reg++) {
                int col = nj*16 + l15;
                int row = wrow*64 + mi*16 + quad*4 + reg;
                ldsT[col*136 + row] = (bf16_t)acc[mi][nj][reg];
              }
        }
        __syncthreads();
        // 64 cols x 16 chunks = 1024 -> 4 passes
#pragma unroll
        for (int pass=0; pass<4; pass++) {
          int idx = pass*256 + t;
          int col = idx >> 4, ch = idx & 15;
          int d = (yb-16)*128 + half*64 + col;
          int hh = d >> 6, cc = d & 63;
          bf16x8 v = *(const bf16x8*)(ldsT + col*136 + ch*8);
          *(bf16x8*)(vT + (((size_t)b*H_ + hh)*KH + cc)*S_ + s0 + ch*8) = v;
        }
      }
    }
    return;
  }

#pragma unroll
  for (int mi=0; mi<WTM; mi++) {
#pragma unroll
    for (int nj=0; nj<WTN; nj++) {
      size_t col = (size_t)by*BN + wcol*(WTN*16) + nj*16 + l15;
#pragma unroll
      for (int reg=0; reg<4; reg++) {
        size_t row = (size_t)bx*BM + wrow*(WTM*16) + mi*16 + quad*4 + reg;
        float v = acc[mi][nj][reg];
        if constexpr (EPI == E_BF16) {
          ((bf16_t*)C)[row*ldc + col] = (bf16_t)v;
        } else if constexpr (EPI == E_GELU) {
          v += bias[col];
          v = gelu_f(v);
          ((bf16_t*)C)[row*ldc + col] = (bf16_t)v;
        } else if constexpr (EPI == E_F32) {
          float* dst = (float*)C + (size_t)seg * ((size_t)gridDim.x * BM) * ldc;
          dst[row*ldc + col] = v;
        } else {  // E_RESF32
          if (bias) v += bias[col];
          v += res[row*(size_t)ldc + col];
          ((float*)C)[row*ldc + col] = v;
        }
      }
    }
  }
}

// ---------- fused phi(k) + kv aggregation ----------
// grid: (8 seg, 64 bh).  kvp fp32 [seg][bh][256 m][80 c]
__global__ __launch_bounds__(256)
void kv_fused(const bf16_t* __restrict__ kb, const float* __restrict__ sqk,
              const bf16_t* __restrict__ omg, const bf16_t* __restrict__ vT,
              float* __restrict__ kvp)
{
  extern __shared__ float4 smem4[];
  char* sm = (char*)smem4;
  bf16_t* PT   = (bf16_t*)sm;             // [256 m][72] (overlaps core As/Bs)
  bf16_t* Vs   = (bf16_t*)(sm + 36864);   // [80 c][64 s] (128B rows, 8 chunks, swizzled)
  float*  stab = (float*)(sm + 47104);    // 256
  float*  comb = (float*)(sm + 48128);    // 64
  const int g = blockIdx.x, bh = blockIdx.y, b = bh >> 4, h = bh & 15;
  const int t=threadIdx.x, lane=t&63, w=t>>6, l15=lane&15, quad=lane>>4;
  const float scale = 0.35355339059327379f;   // 64^-0.25

#pragma unroll
  for (int j=0;j<4;j++){
    int idx = j*256 + t;
    int r = 64 + (idx>>6), s = idx & 63;
    Vs[r*64 + s] = (bf16_t)((r==64) ? 1.0f : 0.0f);
  }

  f32x4 acc2[4][5];
#pragma unroll
  for (int i=0;i<4;i++)
#pragma unroll
    for (int j=0;j<5;j++) acc2[i][j] = f32x4{0.f,0.f,0.f,0.f};

  for (int ch=0; ch<8; ch++) {
    const int s0 = g*512 + ch*64;
    const bf16_t* At = kb + ((size_t)b*S_ + s0)*D_ + h*KH;
    f32x4 acc[4][4];
    gemm_bt_core<64,256,1,4,4,4>(At, D_, omg, KH, KH, sm, acc);

#pragma unroll
    for (int mi=0; mi<4; mi++) {
#pragma unroll
      for (int reg=0; reg<4; reg++) {
        float mx = fmaxf(fmaxf(acc[mi][0][reg], acc[mi][1][reg]),
                         fmaxf(acc[mi][2][reg], acc[mi][3][reg]));
#pragma unroll
        for (int off=1; off<16; off<<=1) mx = fmaxf(mx, __shfl_xor(mx, off, 64));
        if (l15 == 0) stab[w*64 + mi*16 + quad*4 + reg] = mx;
      }
    }
    __syncthreads();
    if (t < 64) {
      float m4 = fmaxf(fmaxf(stab[t], stab[64+t]), fmaxf(stab[128+t], stab[192+t]));
      comb[t] = m4*scale + sqk[(size_t)bh*S_ + s0 + t];
    }
    __syncthreads();
#pragma unroll
    for (int mi=0; mi<4; mi++)
#pragma unroll
      for (int nj=0; nj<4; nj++)
#pragma unroll
        for (int reg=0; reg<4; reg++) {
          int row = mi*16 + quad*4 + reg;          // s-local
          int col = w*64 + nj*16 + l15;            // m
          float p = __expf(scale*acc[mi][nj][reg] - comb[row]) * 0.0625f + 1e-6f;
          PT[col*72 + row] = (bf16_t)p;
        }
#pragma unroll
    for (int ii=0; ii<2; ii++) {
      int c2 = ii*256 + t;
      int cw = ii*256 + (t & ~63);
      int r  = c2 >> 3;
      int js = (c2 & 7) ^ (r & 7);
      async_copy16(vT + ((size_t)bh*KH + r)*S_ + s0 + js*8,
                   (char*)Vs + (size_t)cw*16);
    }
    __syncthreads();
#pragma unroll
    for (int ks=0; ks<2; ks++) {
      bf16x8 af[4];
#pragma unroll
      for (int mi=0; mi<4; mi++)
        af[mi] = *(const bf16x8*)(PT + (w*64 + mi*16 + l15)*72 + ks*32 + quad*8);
#pragma unroll
      for (int nj=0; nj<5; nj++) {
        int rr = nj*16 + l15;
        int slot = (ks*4 + quad) ^ (rr & 7);
        bf16x8 bv = *(const bf16x8*)(Vs + rr*64 + slot*8);
#pragma unroll
        for (int mi=0; mi<4; mi++)
          acc2[mi][nj] = MFMA16(af[mi], bv, acc2[mi][nj]);
      }
    }
  }

#pragma unroll
  for (int mi=0; mi<4; mi++)
#pragma unroll
    for (int nj=0; nj<5; nj++)
#pragma unroll
      for (int reg=0; reg<4; reg++) {
        int m = w*64 + mi*16 + quad*4 + reg;
        int c = nj*16 + l15;
        kvp[(((size_t)g*64 + bh)*256 + m)*80 + c] = acc2[mi][nj][reg];
      }
}

// reduce 8 segments -> kvT[bh][c][m] fp16; grid (4 mblk, 64 bh)
__global__ __launch_bounds__(256)
void kvred_kernel(const float* __restrict__ kvp, bf16_t* __restrict__ kvT)
{
  __shared__ float accs[64*81];
  const int mb = blockIdx.x, bh = blockIdx.y, t = threadIdx.x;
  const int m0 = mb*64;
  float r[20];
#pragma unroll
  for (int i=0;i<20;i++) r[i] = 0.f;
  for (int g2=0; g2<8; g2++) {
    const float* p = kvp + (((size_t)g2*64 + bh)*256 + m0)*80;
#pragma unroll
    for (int i=0;i<20;i++) r[i] += p[i*256 + t];
  }
#pragma unroll
  for (int i=0;i<20;i++) {
    int idx = i*256 + t;           // = mloc*80 + c
    int ml = idx / 80, cc = idx - ml*80;
    accs[ml*81 + cc] = r[i];
  }
  __syncthreads();
  bf16_t* o = kvT + (size_t)bh*(80*M_);
#pragma unroll
  for (int i=0;i<20;i++) {
    int idx2 = i*256 + t;          // = c*64 + mloc
    int c = idx2 >> 6, ml = idx2 & 63;
    o[(size_t)c*M_ + m0 + ml] = (bf16_t)accs[ml*81 + c];
  }
}

// ---------- fused phi(q) + num/den ----------
__global__ __launch_bounds__(256)
void numden_fused(const bf16_t* __restrict__ qb, const float* __restrict__ sqv,
                  const bf16_t* __restrict__ omg, const bf16_t* __restrict__ kvT,
                  bf16_t* __restrict__ attn)
{
  extern __shared__ float4 smem4[];
  char* sm = (char*)smem4;
  bf16_t* P    = (bf16_t*)sm;             // [64 s][264 m] (overlaps core As/Bs)
  char*   Bs2  = sm + 33792;              // 80 rows x 64B (4 chunks, swizzled)
  float*  stab = (float*)(sm + 38912);
  float*  comb = (float*)(sm + 39936);
  const int bh = blockIdx.y, b = bh >> 4, h = bh & 15;
  const int s0 = blockIdx.x * 64;
  const bf16_t* At = qb + ((size_t)b*S_ + s0)*D_ + h*KH;
  f32x4 acc[4][4];
  gemm_bt_core<64,256,1,4,4,4>(At, D_, omg, KH, KH, sm, acc);

  const int t=threadIdx.x, lane=t&63, w=t>>6, l15=lane&15, quad=lane>>4;
  const float scale = 0.35355339059327379f;

#pragma unroll
  for (int mi=0; mi<4; mi++) {
#pragma unroll
    for (int reg=0; reg<4; reg++) {
      float mx = fmaxf(fmaxf(acc[mi][0][reg], acc[mi][1][reg]),
                       fmaxf(acc[mi][2][reg], acc[mi][3][reg]));
#pragma unroll
      for (int off=1; off<16; off<<=1) mx = fmaxf(mx, __shfl_xor(mx, off, 64));
      if (l15 == 0) stab[w*64 + mi*16 + quad*4 + reg] = mx;
    }
  }
  __syncthreads();
  if (t < 64) {
    float m4 = fmaxf(fmaxf(stab[t], stab[64+t]), fmaxf(stab[128+t], stab[192+t]));
    comb[t] = m4*scale + sqv[(size_t)bh*S_ + s0 + t];
  }
  __syncthreads();
#pragma unroll
  for (int mi=0; mi<4; mi++)
#pragma unroll
    for (int nj=0; nj<4; nj++)
#pragma unroll
      for (int reg=0; reg<4; reg++) {
        int row = mi*16 + quad*4 + reg;
        int col = w*64 + nj*16 + l15;
        float p = __expf(scale*acc[mi][nj][reg] - comb[row]) * 0.0625f + 1e-6f;
        P[row*264 + col] = (bf16_t)p;
      }

  const bf16_t* Bt = kvT + (size_t)bh*80*M_;
  f32x4 acc2[5];
#pragma unroll
  for (int j=0;j<5;j++) acc2[j] = f32x4{0.f,0.f,0.f,0.f};

  for (int kk = 0; kk < 256; kk += 32) {
    __syncthreads();
    {
      int c = t, cw = (t & ~63);
      int r = c >> 2;
      int js = (c & 3) ^ ((r >> 1) & 3);
      async_copy16(Bt + (size_t)r*M_ + kk + js*8, Bs2 + (size_t)cw*16);
    }
    if (t < 64) {
      int c = 256 + t;
      int r = c >> 2;
      int js = (c & 3) ^ ((r >> 1) & 3);
      async_copy16(Bt + (size_t)r*M_ + kk + js*8, Bs2 + (size_t)256*16);
    }
    __syncthreads();
    bf16x8 af = *(const bf16x8*)(P + (w*16 + l15)*264 + kk + quad*8);
#pragma unroll
    for (int nj=0; nj<5; nj++) {
      int rn = nj*16 + l15;
      int sw = quad ^ ((rn >> 1) & 3);
      bf16x8 bv = *(const bf16x8*)(Bs2 + rn*64 + sw*16);
      acc2[nj] = MFMA16(af, bv, acc2[nj]);
    }
  }

#pragma unroll
  for (int reg=0; reg<4; reg++) {
    float den = __shfl(acc2[4][reg], (lane & 48), 64);
    int row = w*16 + quad*4 + reg;
#pragma unroll
    for (int nj=0; nj<4; nj++) {
      float v = acc2[nj][reg] / den;
      attn[((size_t)b*S_ + s0 + row)*D_ + h*KH + nj*16 + l15] = (bf16_t)v;
    }
  }
}

// ---------- small kernels ----------
__global__ __launch_bounds__(256)
void cvt_kernel(const float* __restrict__ in, bf16_t* __restrict__ out)
{
  const size_t i = ((size_t)blockIdx.x*256 + threadIdx.x)*4;
  const float4 a = *(const float4*)(in + i);
  bf16x4 o; o[0]=(bf16_t)a.x; o[1]=(bf16_t)a.y; o[2]=(bf16_t)a.z; o[3]=(bf16_t)a.w;
  *(bf16x4*)(out + i) = o;
}

__global__ __launch_bounds__(256)
void tcvt_kernel(const float* __restrict__ in, bf16_t* __restrict__ out, int R, int C)
{
  __shared__ float tile[64][65];
  const int r0 = blockIdx.y*64, c0 = blockIdx.x*64;
  const int tx = threadIdx.x & 63, ty = threadIdx.x >> 6;
  for (int i=ty; i<64; i+=4) tile[i][tx] = in[(size_t)(r0+i)*C + c0 + tx];
  __syncthreads();
  for (int i=ty; i<64; i+=4) out[(size_t)(c0+i)*R + r0 + tx] = (bf16_t)tile[tx][i];
}

// merged wq/wk/wv transpose (1024x1024 each) -> stacked wqkvT; grid (16, 48)
__global__ __launch_bounds__(256)
void tcvt3_kernel(const float* __restrict__ wqp, const float* __restrict__ wkp,
                  const float* __restrict__ wvp, bf16_t* __restrict__ out)
{
  __shared__ float tile[64][65];
  const int sel = blockIdx.y >> 4, ry = blockIdx.y & 15;
  const float* in = (sel==0) ? wqp : (sel==1) ? wkp : wvp;
  bf16_t* o = out + (size_t)sel*D_*D_;
  const int r0 = ry*64, c0 = blockIdx.x*64;
  const int tx = threadIdx.x & 63, ty = threadIdx.x >> 6;
  for (int i=ty; i<64; i+=4) tile[i][tx] = in[(size_t)(r0+i)*D_ + c0 + tx];
  __syncthreads();
  for (int i=ty; i<64; i+=4) o[(size_t)(c0+i)*D_ + r0 + tx] = (bf16_t)tile[tx][i];
}

// merged sq for q and k: blocks 0..4095 -> qb rows, 4096..8191 -> kb rows
__global__ __launch_bounds__(256)
void sq2_kernel(const bf16_t* __restrict__ qkv, float* __restrict__ sqq,
                float* __restrict__ sqk)
{
  const int bi   = blockIdx.x;
  const int ksel = bi >> 12;
  const int i    = ((bi & 4095)<<2) + (threadIdx.x>>6);
  const int lane = threadIdx.x & 63;
  const bf16_t* row = qkv + (size_t)ksel*BSDc + (size_t)i*D_ + lane*16;
  bf16x8 v0 = *(const bf16x8*)row;
  bf16x8 v1 = *(const bf16x8*)(row + 8);
  float s = 0.f;
#pragma unroll
  for (int j=0;j<8;j++){ float a=(float)v0[j], c=(float)v1[j]; s += a*a + c*c; }
  s += __shfl_xor(s, 1, 64);
  s += __shfl_xor(s, 2, 64);
  if ((lane&3)==0) {
    const int h = lane>>2, b = i>>12, ss = i & 4095;
    float* sq = ksel ? sqk : sqq;
    sq[((size_t)b*H_ + h)*S_ + ss] = 0.0625f * s;
  }
}

// fused split-K reduce + residual + LN1 + fp16 copy; one block per row.
// a = p2[0][row] + p2[1][row] + res[row] (res = original x, no bias on out-proj)
// outf = LN1(a) fp32; outb = same in fp16.
__global__ __launch_bounds__(256)
void ln1red_kernel(const float* __restrict__ p2, const float* __restrict__ res,
                   const float* __restrict__ g, const float* __restrict__ bt,
                   float* __restrict__ outf, bf16_t* __restrict__ outb)
{
  __shared__ float rs[4], rs2[4];
  const size_t row = blockIdx.x;
  const int t = threadIdx.x;
  const float4 a0 = ((const float4*)(p2 + row*D_))[t];
  const float4 a1 = ((const float4*)(p2 + BSDc + row*D_))[t];
  const float4 rr = ((const float4*)(res + row*D_))[t];
  float4 a;
  a.x = a0.x + a1.x + rr.x;
  a.y = a0.y + a1.y + rr.y;
  a.z = a0.z + a1.z + rr.z;
  a.w = a0.w + a1.w + rr.w;
  float s  = a.x+a.y+a.z+a.w;
  float s2 = a.x*a.x + a.y*a.y + a.z*a.z + a.w*a.w;
#pragma unroll
  for (int off=32; off; off>>=1) { s += __shfl_xor(s, off, 64); s2 += __shfl_xor(s2, off, 64); }
  if ((t&63)==0) { rs[t>>6]=s; rs2[t>>6]=s2; }
  __syncthreads();
  const float S1 = rs[0]+rs[1]+rs[2]+rs[3];
  const float S2 = rs2[0]+rs2[1]+rs2[2]+rs2[3];
  const float mu   = S1 * (1.f/1024.f);
  const float rstd = rsqrtf(S2 * (1.f/1024.f) - mu*mu + 1e-6f);
  const float4 gg = ((const float4*)g)[t];
  const float4 bb = ((const float4*)bt)[t];
  float4 oo;
  oo.x = (a.x-mu)*rstd*gg.x + bb.x;
  oo.y = (a.y-mu)*rstd*gg.y + bb.y;
  oo.z = (a.z-mu)*rstd*gg.z + bb.z;
  oo.w = (a.w-mu)*rstd*gg.w + bb.w;
  ((float4*)(outf + row*D_))[t] = oo;
  bf16x4 ob; ob[0]=(bf16_t)oo.x; ob[1]=(bf16_t)oo.y; ob[2]=(bf16_t)oo.z; ob[3]=(bf16_t)oo.w;
  *(bf16x4*)(outb + row*D_ + t*4) = ob;
}

// fused split-K reduce + bias + residual + LN2; one block per row.
// a = p2[0][row] + p2[1][row] + b2 + y1[row]; out = LN(a). In-place-per-row
// safe vs res==out (all reads precede the row's writes).
__global__ __launch_bounds__(256)
void ln2red_kernel(const float* __restrict__ p2, const float* __restrict__ bias,
                   const float* __restrict__ res, const float* __restrict__ g,
                   const float* __restrict__ bt, float* __restrict__ outp)
{
  __shared__ float rs[4], rs2[4];
  const size_t row = blockIdx.x;
  const int t = threadIdx.x;
  const float4 a0 = ((const float4*)(p2 + row*D_))[t];
  const float4 a1 = ((const float4*)(p2 + BSDc + row*D_))[t];
  const float4 bb2 = ((const float4*)bias)[t];
  const float4 rr = ((const float4*)(res + row*D_))[t];
  float4 a;
  a.x = a0.x + a1.x + bb2.x + rr.x;
  a.y = a0.y + a1.y + bb2.y + rr.y;
  a.z = a0.z + a1.z + bb2.z + rr.z;
  a.w = a0.w + a1.w + bb2.w + rr.w;
  float s  = a.x+a.y+a.z+a.w;
  float s2 = a.x*a.x + a.y*a.y + a.z*a.z + a.w*a.w;
#pragma unroll
  for (int off=32; off; off>>=1) { s += __shfl_xor(s, off, 64); s2 += __shfl_xor(s2, off, 64); }
  if ((t&63)==0) { rs[t>>6]=s; rs2[t>>6]=s2; }
  __syncthreads();
  const float S1 = rs[0]+rs[1]+rs[2]+rs[3];
  const float S2 = rs2[0]+rs2[1]+rs2[2]+rs2[3];
  const float mu   = S1 * (1.f/1024.f);
  const float rstd = rsqrtf(S2 * (1.f/1024.f) - mu*mu + 1e-6f);
  const float4 gg = ((const float4*)g)[t];
  const float4 bb = ((const float4*)bt)[t];
  float4 oo;
  oo.x = (a.x-mu)*rstd*gg.x + bb.x;
  oo.y = (a.y-mu)*rstd*gg.y + bb.y;
  oo.z = (a.z-mu)*rstd*gg.z + bb.z;
  oo.w = (a.w-mu)*rstd*gg.w + bb.w;
  ((float4*)(outp + row*D_))[t] = oo;
}

// ---------- load-time fallback workspace ----------
// Alloc-list sum = 474.5 MB; 480 MB gives headroom + alignment pad.
static const size_t NEED = 480000000;
static void* g_fb = nullptr;
struct FbInit {
  FbInit() { if (hipMalloc(&g_fb, NEED) != hipSuccess) g_fb = nullptr; }
};
static FbInit g_fbinit;

// ---------- launcher ----------
extern "C" void kernel_launch(void* const* d_in, const int* in_sizes, int n_in,
                              void* d_out, int out_size, void* d_ws, size_t ws_size,
                              hipStream_t stream)
{
  (void)in_sizes; (void)n_in; (void)out_size;
  const float* x     = (const float*)d_in[0];
  const float* wq    = (const float*)d_in[1];
  const float* wk    = (const float*)d_in[2];
  const float* wv    = (const float*)d_in[3];
  const float* wo    = (const float*)d_in[4];
  const float* omega = (const float*)d_in[5];
  const float* ln1g  = (const float*)d_in[6];
  const float* ln1b  = (const float*)d_in[7];
  const float* w1    = (const float*)d_in[8];
  const float* b1    = (const float*)d_in[9];
  const float* w2    = (const float*)d_in[10];
  const float* b2    = (const float*)d_in[11];
  const float* ln2g  = (const float*)d_in[12];
  const float* ln2b  = (const float*)d_in[13];
  float* out = (float*)d_out;

  char* ws = (ws_size >= NEED) ? (char*)d_ws : (char*)g_fb;
  if (!ws) return;

  size_t o = 0;
  auto alloc = [&](size_t bytes) -> char* {
    char* p = ws + o; o += (bytes + 255) & ~(size_t)255; return p;
  };
  const size_t BSD = BSDc;

  bf16_t* wqkvT = (bf16_t*)alloc((size_t)3*D_*D_*2);      // stacked q|k|v B^T
  bf16_t* woT   = (bf16_t*)alloc((size_t)D_*D_*2);
  bf16_t* w1T   = (bf16_t*)alloc((size_t)D_*FF_*2);
  bf16_t* w2T   = (bf16_t*)alloc((size_t)D_*FF_*2);
  bf16_t* omg   = (bf16_t*)alloc((size_t)M_*KH*2);
  float*  sqq   = (float*)alloc((size_t)B_*H_*S_*4);
  float*  sqk   = (float*)alloc((size_t)B_*H_*S_*4);
  bf16_t* kvT   = (bf16_t*)alloc((size_t)B_*H_*80*M_*2);
  float*  kvp   = (float*)alloc((size_t)8*64*256*80*4);   // 42 MB

  bf16_t* xb    = (bf16_t*)alloc(BSD*2);                  // -> x1b
  bf16_t* qkv   = (bf16_t*)alloc(3*BSD*2);                // qb | kb | vT contiguous
  bf16_t* h1    = (bf16_t*)alloc(BSD*4*2);                // 128 MB fp16 [16384][4096]
  float*  p2    = (float*)alloc(2*BSD*4);                 // 128 MB fp32 split-K partials

  bf16_t* x1b  = xb;
  bf16_t* qb   = qkv;
  bf16_t* kb   = qkv + BSD;
  bf16_t* vT   = qkv + 2*BSD;
  bf16_t* attn = qb;              // in-place over qb
  float*  y1   = (float*)d_out;   // fp32 x1 (LN1 out) lives in d_out until LN2

  constexpr int SH128 = (128+128)*64;      // 16384
  constexpr int SHQKV = 64*136*2;          // 17408 (>= core 16384)
  constexpr int SHKF  = 48384;
  constexpr int SHND  = 40192;

  // 1. converts / weight transposes
  cvt_kernel<<<(int)(BSD/1024), 256, 0, stream>>>(x, xb);
  tcvt3_kernel<<<dim3(16,48), 256, 0, stream>>>(wq, wk, wv, wqkvT);
  tcvt_kernel<<<dim3(16,16), 256, 0, stream>>>(wo, woT, 1024, 1024);
  tcvt_kernel<<<dim3(64,16), 256, 0, stream>>>(w1, w1T, 1024, 4096);
  tcvt_kernel<<<dim3(16,64), 256, 0, stream>>>(w2, w2T, 4096, 1024);
  cvt_kernel<<<16, 256, 0, stream>>>(omega, omg);

  // 2. merged QKV projection: [16384,1024] x [3072,1024]^T, 3072 blocks
  gemm_bt_kernel<128,128,2,2,4,4,E_QKV><<<dim3(128,24), 256, SHQKV, stream>>>(
      xb, D_, wqkvT, D_, qkv, D_, D_, nullptr, nullptr);

  // 3. sq (merged q+k)
  sq2_kernel<<<8192, 256, 0, stream>>>(qkv, sqq, sqk);

  // 4. fused phi(k)+kv aggregation (8 segments = 512 blocks), then reduce
  kv_fused<<<dim3(8,64), 256, SHKF, stream>>>(kb, sqk, omg, vT, kvp);
  kvred_kernel<<<dim3(4,64), 256, 0, stream>>>(kvp, kvT);

  // 5. fused phi(q)+num/den -> attn (in place over qb)
  numden_fused<<<dim3(64,64), 256, SHND, stream>>>(qb, sqq, omg, kvT, attn);

  // 6. out projection split-K=2 (2048 blocks, K=512/seg -> p2 partials),
  //    then fused reduce + residual(x) + LN1 -> y1 fp32 + x1b fp16
  gemm_bt_kernel<128,128,2,2,4,4,E_F32><<<dim3(128,16), 256, SH128, stream>>>(
      attn, D_, woT, D_, p2, D_, 512, nullptr, nullptr);
  ln1red_kernel<<<B_*S_, 256, 0, stream>>>(p2, x, ln1g, ln1b, y1, x1b);

  // 7. FFN1 (4096 blocks); FFN2 split-K=2 (2048 blocks, K=2048/seg -> p2 partials)
  gemm_bt_kernel<128,128,2,2,4,4,E_GELU><<<dim3(128,32), 256, SH128, stream>>>(
      x1b, D_, w1T, D_, h1, FF_, D_, b1, nullptr);
  gemm_bt_kernel<128,128,2,2,4,4,E_F32><<<dim3(128,16), 256, SH128, stream>>>(
      h1, FF_, w2T, FF_, p2, D_, 2048, nullptr, nullptr);

  // 8. fused reduce + b2 + residual(y1) + LN2 -> output
  ln2red_kernel<<<B_*S_, 256, 0, stream>>>(p2, b2, y1, ln2g, ln2b, out);
}

// Round 10
// 1104.634 us; speedup vs baseline: 1.1478x; 1.0257x over previous
//
#include <hip/hip_runtime.h>
#include <cstdint>
#include <cstddef>

// ---------- problem constants ----------
#define B_   4
#define S_   4096
#define D_   1024
#define H_   16
#define KH   64
#define M_   256
#define FF_  4096

// fp16 compute path (same MFMA rate as bf16, lower quantization error)
typedef _Float16 bf16_t;
typedef _Float16 bf16x8 __attribute__((ext_vector_type(8)));
typedef _Float16 bf16x4 __attribute__((ext_vector_type(4)));
typedef float    f32x4  __attribute__((ext_vector_type(4)));

#define MFMA16(a,b,c) __builtin_amdgcn_mfma_f32_16x16x32_f16((a),(b),(c),0,0,0)

static constexpr size_t BSDc = (size_t)B_*S_*D_;   // 16,777,216 elements

// ---------- async global->LDS, 16B per lane ----------
__device__ __forceinline__ void async_copy16(const void* gp, void* lp) {
  auto g = reinterpret_cast<const __attribute__((address_space(1))) void*>(
      reinterpret_cast<uintptr_t>(gp));
  auto l = reinterpret_cast<__attribute__((address_space(3))) void*>(
      reinterpret_cast<uintptr_t>(lp));
  __builtin_amdgcn_global_load_lds(g, l, 16, 0, 0);
}

// ---------- generic B^T GEMM core (XOR bank-swizzled LDS tiles) ----------
template<int BM,int BN,int WROWS,int WCOLS,int WTM,int WTN>
__device__ __forceinline__ void gemm_bt_core(
    const bf16_t* __restrict__ At, int lda,
    const bf16_t* __restrict__ Bt, int ldb,
    int Kd, char* sm, f32x4 (&acc)[WTM][WTN])
{
  constexpr int NT = WROWS*WCOLS*64;
  static_assert(WROWS*WTM*16 == BM && WCOLS*WTN*16 == BN, "tile mismatch");
  const int t    = threadIdx.x;
  const int lane = t & 63;
  const int w    = t >> 6;
  const int wrow = w / WCOLS, wcol = w % WCOLS;
  const int l15  = lane & 15, quad = lane >> 4;
  char* As = sm;
  char* Bs = sm + BM*64;

#pragma unroll
  for (int i=0;i<WTM;i++)
#pragma unroll
    for (int j=0;j<WTN;j++)
      acc[i][j] = f32x4{0.f,0.f,0.f,0.f};

  constexpr int CA = BM*4;
  static_assert(CA % NT == 0, "A staging must be whole issues");
  constexpr int AI    = CA / NT;
  constexpr int BFULL = (BN*4) / NT;
  constexpr int BREM  = (BN*4) % NT;

  for (int kk = 0; kk < Kd; kk += 32) {
    __syncthreads();
#pragma unroll
    for (int ii=0; ii<AI; ii++) {
      int c  = ii*NT + t;
      int cw = ii*NT + (t & ~63);
      int r  = c >> 2;
      int js = (c & 3) ^ ((r >> 1) & 3);         // swizzled source chunk
      async_copy16(At + (size_t)r*lda + kk + js*8, As + (size_t)cw*16);
    }
#pragma unroll
    for (int ii=0; ii<BFULL; ii++) {
      int c  = ii*NT + t;
      int cw = ii*NT + (t & ~63);
      int r  = c >> 2;
      int js = (c & 3) ^ ((r >> 1) & 3);
      async_copy16(Bt + (size_t)r*ldb + kk + js*8, Bs + (size_t)cw*16);
    }
    if constexpr (BREM != 0) {
      if (t < BREM) {
        int c  = BFULL*NT + t;
        int cw = BFULL*NT + (t & ~63);
        int r  = c >> 2;
        int js = (c & 3) ^ ((r >> 1) & 3);
        async_copy16(Bt + (size_t)r*ldb + kk + js*8, Bs + (size_t)cw*16);
      }
    }
    __syncthreads();

    bf16x8 af[WTM], bv[WTN];
#pragma unroll
    for (int mi=0; mi<WTM; mi++) {
      int row = wrow*(WTM*16) + mi*16 + l15;
      int sw  = quad ^ ((row >> 1) & 3);
      af[mi] = *(const bf16x8*)(As + row*64 + sw*16);
    }
#pragma unroll
    for (int nj=0; nj<WTN; nj++) {
      int rn = wcol*(WTN*16) + nj*16 + l15;
      int sw = quad ^ ((rn >> 1) & 3);
      bv[nj] = *(const bf16x8*)(Bs + rn*64 + sw*16);
    }
#pragma unroll
    for (int mi=0; mi<WTM; mi++)
#pragma unroll
      for (int nj=0; nj<WTN; nj++)
        acc[mi][nj] = MFMA16(af[mi], bv[nj], acc[mi][nj]);
  }
}

// ---------- epilogue variants ----------
enum { E_BF16 = 0, E_GELU = 2, E_RESF32 = 3, E_QKV = 5, E_F32 = 6 };

// exact-GELU via A&S 7.1.26 erf approximation (|err| ~1.5e-7).
__device__ __forceinline__ float gelu_f(float v) {
  float u  = v * 0.70710678118654752f;
  float au = fabsf(u);
  float tt = __builtin_amdgcn_rcpf(1.0f + 0.3275911f*au);
  float poly = tt*(0.254829592f + tt*(-0.284496736f + tt*(1.421413741f +
               tt*(-1.453152027f + tt*1.061405429f))));
  float er = 1.0f - poly*__expf(-au*au);
  er = __builtin_copysignf(er, u);
  return 0.5f * v * (1.0f + er);
}

template<int BM,int BN,int WROWS,int WCOLS,int WTM,int WTN,int EPI>
__global__ __launch_bounds__(WROWS*WCOLS*64)
void gemm_bt_kernel(const bf16_t* __restrict__ A, int lda,
                    const bf16_t* __restrict__ Bt, int ldb,
                    void* __restrict__ C, int ldc,
                    int Kd, const float* __restrict__ bias, const float* __restrict__ res)
{
  extern __shared__ float4 smem4[];
  char* sm = (char*)smem4;

  // XCD-aware bijective swizzle (T1): each XCD owns a contiguous work chunk ->
  // its B-panel stays resident in that XCD's 4MB L2 (grids here are %8==0).
  const int nbx = gridDim.x;
  const int nwg = nbx * gridDim.y;
  int bx, by;
  {
    int orig = blockIdx.y * nbx + blockIdx.x;
    if ((nwg & 7) == 0) {
      int swz = (orig & 7) * (nwg >> 3) + (orig >> 3);
      bx = swz % nbx; by = swz / nbx;
    } else { bx = blockIdx.x; by = blockIdx.y; }
  }

  // E_F32 = split-K partials: by>>3 selects K-segment, by&7 the N-panel
  // (8 N-panels of BN=128).
  int seg = 0;
  if constexpr (EPI == E_F32) { seg = by >> 3; by &= 7; }
  const int koff = seg * Kd;

  const bf16_t* At  = A  + (size_t)bx*BM*lda + koff;
  const bf16_t* Bt2 = Bt + (size_t)by*BN*ldb + koff;
  f32x4 acc[WTM][WTN];
  gemm_bt_core<BM,BN,WROWS,WCOLS,WTM,WTN>(At, lda, Bt2, ldb, Kd, sm, acc);

  const int t=threadIdx.x, lane=t&63, w=t>>6;
  const int wrow=w/WCOLS, wcol=w%WCOLS, l15=lane&15, quad=lane>>4;

  if constexpr (EPI == E_QKV) {
    // merged QKV: by 0..7 -> q, 8..15 -> k, 16..23 -> vT (transposed)
    const int yb = by;
    bf16_t* base = (bf16_t*)C;              // qb; kb = +BSD; vT = +2*BSD
    if (yb < 16) {
      bf16_t* dst = base + (size_t)(yb >> 3) * BSDc;
      const size_t colbase = (size_t)(yb & 7) * 128;
#pragma unroll
      for (int mi=0; mi<WTM; mi++)
#pragma unroll
        for (int nj=0; nj<WTN; nj++) {
          size_t col = colbase + wcol*64 + nj*16 + l15;
#pragma unroll
          for (int reg=0; reg<4; reg++) {
            size_t row = (size_t)bx*128 + wrow*64 + mi*16 + quad*4 + reg;
            dst[row*D_ + col] = (bf16_t)acc[mi][nj][reg];
          }
        }
    } else {
      bf16_t* vT = base + 2*BSDc;
      bf16_t* ldsT = (bf16_t*)sm;           // [64 cols][136 rows]
      const int b  = (bx*128) >> 12;
      const int s0 = (bx*128) & 4095;
#pragma unroll
      for (int half=0; half<2; half++) {
        __syncthreads();                    // core LDS reads done / prev drain done
        if (wcol == half) {
#pragma unroll
          for (int mi=0; mi<WTM; mi++)
#pragma unroll
            for (int nj=0; nj<WTN; nj++)
#pragma unroll
              for (int reg=0; reg<4; reg++) {
                int col = nj*16 + l15;
                int row = wrow*64 + mi*16 + quad*4 + reg;
                ldsT[col*136 + row] = (bf16_t)acc[mi][nj][reg];
              }
        }
        __syncthreads();
        // 64 cols x 16 chunks = 1024 -> 4 passes
#pragma unroll
        for (int pass=0; pass<4; pass++) {
          int idx = pass*256 + t;
          int col = idx >> 4, ch = idx & 15;
          int d = (yb-16)*128 + half*64 + col;
          int hh = d >> 6, cc = d & 63;
          bf16x8 v = *(const bf16x8*)(ldsT + col*136 + ch*8);
          *(bf16x8*)(vT + (((size_t)b*H_ + hh)*KH + cc)*S_ + s0 + ch*8) = v;
        }
      }
    }
    return;
  }

#pragma unroll
  for (int mi=0; mi<WTM; mi++) {
#pragma unroll
    for (int nj=0; nj<WTN; nj++) {
      size_t col = (size_t)by*BN + wcol*(WTN*16) + nj*16 + l15;
#pragma unroll
      for (int reg=0; reg<4; reg++) {
        size_t row = (size_t)bx*BM + wrow*(WTM*16) + mi*16 + quad*4 + reg;
        float v = acc[mi][nj][reg];
        if constexpr (EPI == E_BF16) {
          ((bf16_t*)C)[row*ldc + col] = (bf16_t)v;
        } else if constexpr (EPI == E_GELU) {
          v += bias[col];
          v = gelu_f(v);
          ((bf16_t*)C)[row*ldc + col] = (bf16_t)v;
        } else if constexpr (EPI == E_F32) {
          float* dst = (float*)C + (size_t)seg * ((size_t)gridDim.x * BM) * ldc;
          dst[row*ldc + col] = v;
        } else {  // E_RESF32
          if (bias) v += bias[col];
          v += res[row*(size_t)ldc + col];
          ((float*)C)[row*ldc + col] = v;
        }
      }
    }
  }
}

// ---------- fused phi(k) + kv aggregation ----------
// grid: (8 seg, 64 bh).  kvp fp32 [seg][bh][256 m][80 c]
__global__ __launch_bounds__(256)
void kv_fused(const bf16_t* __restrict__ kb, const float* __restrict__ sqk,
              const bf16_t* __restrict__ omg, const bf16_t* __restrict__ vT,
              float* __restrict__ kvp)
{
  extern __shared__ float4 smem4[];
  char* sm = (char*)smem4;
  bf16_t* PT   = (bf16_t*)sm;             // [256 m][72] (overlaps core As/Bs)
  bf16_t* Vs   = (bf16_t*)(sm + 36864);   // [80 c][64 s] (128B rows, 8 chunks, swizzled)
  float*  stab = (float*)(sm + 47104);    // 256
  float*  comb = (float*)(sm + 48128);    // 64
  const int g = blockIdx.x, bh = blockIdx.y, b = bh >> 4, h = bh & 15;
  const int t=threadIdx.x, lane=t&63, w=t>>6, l15=lane&15, quad=lane>>4;
  const float scale = 0.35355339059327379f;   // 64^-0.25

#pragma unroll
  for (int j=0;j<4;j++){
    int idx = j*256 + t;
    int r = 64 + (idx>>6), s = idx & 63;
    Vs[r*64 + s] = (bf16_t)((r==64) ? 1.0f : 0.0f);
  }

  f32x4 acc2[4][5];
#pragma unroll
  for (int i=0;i<4;i++)
#pragma unroll
    for (int j=0;j<5;j++) acc2[i][j] = f32x4{0.f,0.f,0.f,0.f};

  for (int ch=0; ch<8; ch++) {
    const int s0 = g*512 + ch*64;
    const bf16_t* At = kb + ((size_t)b*S_ + s0)*D_ + h*KH;
    f32x4 acc[4][4];
    gemm_bt_core<64,256,1,4,4,4>(At, D_, omg, KH, KH, sm, acc);

#pragma unroll
    for (int mi=0; mi<4; mi++) {
#pragma unroll
      for (int reg=0; reg<4; reg++) {
        float mx = fmaxf(fmaxf(acc[mi][0][reg], acc[mi][1][reg]),
                         fmaxf(acc[mi][2][reg], acc[mi][3][reg]));
#pragma unroll
        for (int off=1; off<16; off<<=1) mx = fmaxf(mx, __shfl_xor(mx, off, 64));
        if (l15 == 0) stab[w*64 + mi*16 + quad*4 + reg] = mx;
      }
    }
    __syncthreads();
    if (t < 64) {
      float m4 = fmaxf(fmaxf(stab[t], stab[64+t]), fmaxf(stab[128+t], stab[192+t]));
      comb[t] = m4*scale + sqk[(size_t)bh*S_ + s0 + t];
    }
    __syncthreads();
#pragma unroll
    for (int mi=0; mi<4; mi++)
#pragma unroll
      for (int nj=0; nj<4; nj++)
#pragma unroll
        for (int reg=0; reg<4; reg++) {
          int row = mi*16 + quad*4 + reg;          // s-local
          int col = w*64 + nj*16 + l15;            // m
          float p = __expf(scale*acc[mi][nj][reg] - comb[row]) * 0.0625f + 1e-6f;
          PT[col*72 + row] = (bf16_t)p;
        }
#pragma unroll
    for (int ii=0; ii<2; ii++) {
      int c2 = ii*256 + t;
      int cw = ii*256 + (t & ~63);
      int r  = c2 >> 3;
      int js = (c2 & 7) ^ (r & 7);
      async_copy16(vT + ((size_t)bh*KH + r)*S_ + s0 + js*8,
                   (char*)Vs + (size_t)cw*16);
    }
    __syncthreads();
#pragma unroll
    for (int ks=0; ks<2; ks++) {
      bf16x8 af[4];
#pragma unroll
      for (int mi=0; mi<4; mi++)
        af[mi] = *(const bf16x8*)(PT + (w*64 + mi*16 + l15)*72 + ks*32 + quad*8);
#pragma unroll
      for (int nj=0; nj<5; nj++) {
        int rr = nj*16 + l15;
        int slot = (ks*4 + quad) ^ (rr & 7);
        bf16x8 bv = *(const bf16x8*)(Vs + rr*64 + slot*8);
#pragma unroll
        for (int mi=0; mi<4; mi++)
          acc2[mi][nj] = MFMA16(af[mi], bv, acc2[mi][nj]);
      }
    }
  }

#pragma unroll
  for (int mi=0; mi<4; mi++)
#pragma unroll
    for (int nj=0; nj<5; nj++)
#pragma unroll
      for (int reg=0; reg<4; reg++) {
        int m = w*64 + mi*16 + quad*4 + reg;
        int c = nj*16 + l15;
        kvp[(((size_t)g*64 + bh)*256 + m)*80 + c] = acc2[mi][nj][reg];
      }
}

// reduce 8 segments -> kvT[bh][c][m] fp16; grid (4 mblk, 64 bh)
__global__ __launch_bounds__(256)
void kvred_kernel(const float* __restrict__ kvp, bf16_t* __restrict__ kvT)
{
  __shared__ float accs[64*81];
  const int mb = blockIdx.x, bh = blockIdx.y, t = threadIdx.x;
  const int m0 = mb*64;
  float r[20];
#pragma unroll
  for (int i=0;i<20;i++) r[i] = 0.f;
  for (int g2=0; g2<8; g2++) {
    const float* p = kvp + (((size_t)g2*64 + bh)*256 + m0)*80;
#pragma unroll
    for (int i=0;i<20;i++) r[i] += p[i*256 + t];
  }
#pragma unroll
  for (int i=0;i<20;i++) {
    int idx = i*256 + t;           // = mloc*80 + c
    int ml = idx / 80, cc = idx - ml*80;
    accs[ml*81 + cc] = r[i];
  }
  __syncthreads();
  bf16_t* o = kvT + (size_t)bh*(80*M_);
#pragma unroll
  for (int i=0;i<20;i++) {
    int idx2 = i*256 + t;          // = c*64 + mloc
    int c = idx2 >> 6, ml = idx2 & 63;
    o[(size_t)c*M_ + m0 + ml] = (bf16_t)accs[ml*81 + c];
  }
}

// ---------- fused phi(q) + num/den ----------
__global__ __launch_bounds__(256)
void numden_fused(const bf16_t* __restrict__ qb, const float* __restrict__ sqv,
                  const bf16_t* __restrict__ omg, const bf16_t* __restrict__ kvT,
                  bf16_t* __restrict__ attn)
{
  extern __shared__ float4 smem4[];
  char* sm = (char*)smem4;
  bf16_t* P    = (bf16_t*)sm;             // [64 s][264 m] (overlaps core As/Bs)
  char*   Bs2  = sm + 33792;              // 80 rows x 64B (4 chunks, swizzled)
  float*  stab = (float*)(sm + 38912);
  float*  comb = (float*)(sm + 39936);
  const int bh = blockIdx.y, b = bh >> 4, h = bh & 15;
  const int s0 = blockIdx.x * 64;
  const bf16_t* At = qb + ((size_t)b*S_ + s0)*D_ + h*KH;
  f32x4 acc[4][4];
  gemm_bt_core<64,256,1,4,4,4>(At, D_, omg, KH, KH, sm, acc);

  const int t=threadIdx.x, lane=t&63, w=t>>6, l15=lane&15, quad=lane>>4;
  const float scale = 0.35355339059327379f;

#pragma unroll
  for (int mi=0; mi<4; mi++) {
#pragma unroll
    for (int reg=0; reg<4; reg++) {
      float mx = fmaxf(fmaxf(acc[mi][0][reg], acc[mi][1][reg]),
                       fmaxf(acc[mi][2][reg], acc[mi][3][reg]));
#pragma unroll
      for (int off=1; off<16; off<<=1) mx = fmaxf(mx, __shfl_xor(mx, off, 64));
      if (l15 == 0) stab[w*64 + mi*16 + quad*4 + reg] = mx;
    }
  }
  __syncthreads();
  if (t < 64) {
    float m4 = fmaxf(fmaxf(stab[t], stab[64+t]), fmaxf(stab[128+t], stab[192+t]));
    comb[t] = m4*scale + sqv[(size_t)bh*S_ + s0 + t];
  }
  __syncthreads();
#pragma unroll
  for (int mi=0; mi<4; mi++)
#pragma unroll
    for (int nj=0; nj<4; nj++)
#pragma unroll
      for (int reg=0; reg<4; reg++) {
        int row = mi*16 + quad*4 + reg;
        int col = w*64 + nj*16 + l15;
        float p = __expf(scale*acc[mi][nj][reg] - comb[row]) * 0.0625f + 1e-6f;
        P[row*264 + col] = (bf16_t)p;
      }

  const bf16_t* Bt = kvT + (size_t)bh*80*M_;
  f32x4 acc2[5];
#pragma unroll
  for (int j=0;j<5;j++) acc2[j] = f32x4{0.f,0.f,0.f,0.f};

  for (int kk = 0; kk < 256; kk += 32) {
    __syncthreads();
    {
      int c = t, cw = (t & ~63);
      int r = c >> 2;
      int js = (c & 3) ^ ((r >> 1) & 3);
      async_copy16(Bt + (size_t)r*M_ + kk + js*8, Bs2 + (size_t)cw*16);
    }
    if (t < 64) {
      int c = 256 + t;
      int r = c >> 2;
      int js = (c & 3) ^ ((r >> 1) & 3);
      async_copy16(Bt + (size_t)r*M_ + kk + js*8, Bs2 + (size_t)256*16);
    }
    __syncthreads();
    bf16x8 af = *(const bf16x8*)(P + (w*16 + l15)*264 + kk + quad*8);
#pragma unroll
    for (int nj=0; nj<5; nj++) {
      int rn = nj*16 + l15;
      int sw = quad ^ ((rn >> 1) & 3);
      bf16x8 bv = *(const bf16x8*)(Bs2 + rn*64 + sw*16);
      acc2[nj] = MFMA16(af, bv, acc2[nj]);
    }
  }

#pragma unroll
  for (int reg=0; reg<4; reg++) {
    float den = __shfl(acc2[4][reg], (lane & 48), 64);
    int row = w*16 + quad*4 + reg;
#pragma unroll
    for (int nj=0; nj<4; nj++) {
      float v = acc2[nj][reg] / den;
      attn[((size_t)b*S_ + s0 + row)*D_ + h*KH + nj*16 + l15] = (bf16_t)v;
    }
  }
}

// ---------- small kernels ----------
__global__ __launch_bounds__(256)
void cvt_kernel(const float* __restrict__ in, bf16_t* __restrict__ out)
{
  const size_t i = ((size_t)blockIdx.x*256 + threadIdx.x)*4;
  const float4 a = *(const float4*)(in + i);
  bf16x4 o; o[0]=(bf16_t)a.x; o[1]=(bf16_t)a.y; o[2]=(bf16_t)a.z; o[3]=(bf16_t)a.w;
  *(bf16x4*)(out + i) = o;
}

__global__ __launch_bounds__(256)
void tcvt_kernel(const float* __restrict__ in, bf16_t* __restrict__ out, int R, int C)
{
  __shared__ float tile[64][65];
  const int r0 = blockIdx.y*64, c0 = blockIdx.x*64;
  const int tx = threadIdx.x & 63, ty = threadIdx.x >> 6;
  for (int i=ty; i<64; i+=4) tile[i][tx] = in[(size_t)(r0+i)*C + c0 + tx];
  __syncthreads();
  for (int i=ty; i<64; i+=4) out[(size_t)(c0+i)*R + r0 + tx] = (bf16_t)tile[tx][i];
}

// merged wq/wk/wv transpose (1024x1024 each) -> stacked wqkvT; grid (16, 48)
__global__ __launch_bounds__(256)
void tcvt3_kernel(const float* __restrict__ wqp, const float* __restrict__ wkp,
                  const float* __restrict__ wvp, bf16_t* __restrict__ out)
{
  __shared__ float tile[64][65];
  const int sel = blockIdx.y >> 4, ry = blockIdx.y & 15;
  const float* in = (sel==0) ? wqp : (sel==1) ? wkp : wvp;
  bf16_t* o = out + (size_t)sel*D_*D_;
  const int r0 = ry*64, c0 = blockIdx.x*64;
  const int tx = threadIdx.x & 63, ty = threadIdx.x >> 6;
  for (int i=ty; i<64; i+=4) tile[i][tx] = in[(size_t)(r0+i)*D_ + c0 + tx];
  __syncthreads();
  for (int i=ty; i<64; i+=4) o[(size_t)(c0+i)*D_ + r0 + tx] = (bf16_t)tile[tx][i];
}

// merged sq for q and k: blocks 0..4095 -> qb rows, 4096..8191 -> kb rows
__global__ __launch_bounds__(256)
void sq2_kernel(const bf16_t* __restrict__ qkv, float* __restrict__ sqq,
                float* __restrict__ sqk)
{
  const int bi   = blockIdx.x;
  const int ksel = bi >> 12;
  const int i    = ((bi & 4095)<<2) + (threadIdx.x>>6);
  const int lane = threadIdx.x & 63;
  const bf16_t* row = qkv + (size_t)ksel*BSDc + (size_t)i*D_ + lane*16;
  bf16x8 v0 = *(const bf16x8*)row;
  bf16x8 v1 = *(const bf16x8*)(row + 8);
  float s = 0.f;
#pragma unroll
  for (int j=0;j<8;j++){ float a=(float)v0[j], c=(float)v1[j]; s += a*a + c*c; }
  s += __shfl_xor(s, 1, 64);
  s += __shfl_xor(s, 2, 64);
  if ((lane&3)==0) {
    const int h = lane>>2, b = i>>12, ss = i & 4095;
    float* sq = ksel ? sqk : sqq;
    sq[((size_t)b*H_ + h)*S_ + ss] = 0.0625f * s;
  }
}

// fused split-K reduce + residual + LN1 + fp16 copy; one block per row.
// a = p2[0][row] + p2[1][row] + res[row] (res = original x, no bias on out-proj)
// outf = LN1(a) fp32; outb = same in fp16.
__global__ __launch_bounds__(256)
void ln1red_kernel(const float* __restrict__ p2, const float* __restrict__ res,
                   const float* __restrict__ g, const float* __restrict__ bt,
                   float* __restrict__ outf, bf16_t* __restrict__ outb)
{
  __shared__ float rs[4], rs2[4];
  const size_t row = blockIdx.x;
  const int t = threadIdx.x;
  const float4 a0 = ((const float4*)(p2 + row*D_))[t];
  const float4 a1 = ((const float4*)(p2 + BSDc + row*D_))[t];
  const float4 rr = ((const float4*)(res + row*D_))[t];
  float4 a;
  a.x = a0.x + a1.x + rr.x;
  a.y = a0.y + a1.y + rr.y;
  a.z = a0.z + a1.z + rr.z;
  a.w = a0.w + a1.w + rr.w;
  float s  = a.x+a.y+a.z+a.w;
  float s2 = a.x*a.x + a.y*a.y + a.z*a.z + a.w*a.w;
#pragma unroll
  for (int off=32; off; off>>=1) { s += __shfl_xor(s, off, 64); s2 += __shfl_xor(s2, off, 64); }
  if ((t&63)==0) { rs[t>>6]=s; rs2[t>>6]=s2; }
  __syncthreads();
  const float S1 = rs[0]+rs[1]+rs[2]+rs[3];
  const float S2 = rs2[0]+rs2[1]+rs2[2]+rs2[3];
  const float mu   = S1 * (1.f/1024.f);
  const float rstd = rsqrtf(S2 * (1.f/1024.f) - mu*mu + 1e-6f);
  const float4 gg = ((const float4*)g)[t];
  const float4 bb = ((const float4*)bt)[t];
  float4 oo;
  oo.x = (a.x-mu)*rstd*gg.x + bb.x;
  oo.y = (a.y-mu)*rstd*gg.y + bb.y;
  oo.z = (a.z-mu)*rstd*gg.z + bb.z;
  oo.w = (a.w-mu)*rstd*gg.w + bb.w;
  ((float4*)(outf + row*D_))[t] = oo;
  bf16x4 ob; ob[0]=(bf16_t)oo.x; ob[1]=(bf16_t)oo.y; ob[2]=(bf16_t)oo.z; ob[3]=(bf16_t)oo.w;
  *(bf16x4*)(outb + row*D_ + t*4) = ob;
}

// fused split-K reduce + bias + residual + LN2; one block per row.
// a = p2[0][row] + p2[1][row] + b2 + y1[row]; out = LN(a). In-place-per-row
// safe vs res==out (all reads precede the row's writes).
__global__ __launch_bounds__(256)
void ln2red_kernel(const float* __restrict__ p2, const float* __restrict__ bias,
                   const float* __restrict__ res, const float* __restrict__ g,
                   const float* __restrict__ bt, float* __restrict__ outp)
{
  __shared__ float rs[4], rs2[4];
  const size_t row = blockIdx.x;
  const int t = threadIdx.x;
  const float4 a0 = ((const float4*)(p2 + row*D_))[t];
  const float4 a1 = ((const float4*)(p2 + BSDc + row*D_))[t];
  const float4 bb2 = ((const float4*)bias)[t];
  const float4 rr = ((const float4*)(res + row*D_))[t];
  float4 a;
  a.x = a0.x + a1.x + bb2.x + rr.x;
  a.y = a0.y + a1.y + bb2.y + rr.y;
  a.z = a0.z + a1.z + bb2.z + rr.z;
  a.w = a0.w + a1.w + bb2.w + rr.w;
  float s  = a.x+a.y+a.z+a.w;
  float s2 = a.x*a.x + a.y*a.y + a.z*a.z + a.w*a.w;
#pragma unroll
  for (int off=32; off; off>>=1) { s += __shfl_xor(s, off, 64); s2 += __shfl_xor(s2, off, 64); }
  if ((t&63)==0) { rs[t>>6]=s; rs2[t>>6]=s2; }
  __syncthreads();
  const float S1 = rs[0]+rs[1]+rs[2]+rs[3];
  const float S2 = rs2[0]+rs2[1]+rs2[2]+rs2[3];
  const float mu   = S1 * (1.f/1024.f);
  const float rstd = rsqrtf(S2 * (1.f/1024.f) - mu*mu + 1e-6f);
  const float4 gg = ((const float4*)g)[t];
  const float4 bb = ((const float4*)bt)[t];
  float4 oo;
  oo.x = (a.x-mu)*rstd*gg.x + bb.x;
  oo.y = (a.y-mu)*rstd*gg.y + bb.y;
  oo.z = (a.z-mu)*rstd*gg.z + bb.z;
  oo.w = (a.w-mu)*rstd*gg.w + bb.w;
  ((float4*)(outp + row*D_))[t] = oo;
}

// ---------- load-time fallback workspace ----------
// Alloc-list sum = 474.5 MB; 480 MB gives headroom + alignment pad.
static const size_t NEED = 480000000;
static void* g_fb = nullptr;
struct FbInit {
  FbInit() { if (hipMalloc(&g_fb, NEED) != hipSuccess) g_fb = nullptr; }
};
static FbInit g_fbinit;

// ---------- launcher ----------
extern "C" void kernel_launch(void* const* d_in, const int* in_sizes, int n_in,
                              void* d_out, int out_size, void* d_ws, size_t ws_size,
                              hipStream_t stream)
{
  (void)in_sizes; (void)n_in; (void)out_size;
  const float* x     = (const float*)d_in[0];
  const float* wq    = (const float*)d_in[1];
  const float* wk    = (const float*)d_in[2];
  const float* wv    = (const float*)d_in[3];
  const float* wo    = (const float*)d_in[4];
  const float* omega = (const float*)d_in[5];
  const float* ln1g  = (const float*)d_in[6];
  const float* ln1b  = (const float*)d_in[7];
  const float* w1    = (const float*)d_in[8];
  const float* b1    = (const float*)d_in[9];
  const float* w2    = (const float*)d_in[10];
  const float* b2    = (const float*)d_in[11];
  const float* ln2g  = (const float*)d_in[12];
  const float* ln2b  = (const float*)d_in[13];
  float* out = (float*)d_out;

  char* ws = (ws_size >= NEED) ? (char*)d_ws : (char*)g_fb;
  if (!ws) return;

  size_t o = 0;
  auto alloc = [&](size_t bytes) -> char* {
    char* p = ws + o; o += (bytes + 255) & ~(size_t)255; return p;
  };
  const size_t BSD = BSDc;

  bf16_t* wqkvT = (bf16_t*)alloc((size_t)3*D_*D_*2);      // stacked q|k|v B^T
  bf16_t* woT   = (bf16_t*)alloc((size_t)D_*D_*2);
  bf16_t* w1T   = (bf16_t*)alloc((size_t)D_*FF_*2);
  bf16_t* w2T   = (bf16_t*)alloc((size_t)D_*FF_*2);
  bf16_t* omg   = (bf16_t*)alloc((size_t)M_*KH*2);
  float*  sqq   = (float*)alloc((size_t)B_*H_*S_*4);
  float*  sqk   = (float*)alloc((size_t)B_*H_*S_*4);
  bf16_t* kvT   = (bf16_t*)alloc((size_t)B_*H_*80*M_*2);
  float*  kvp   = (float*)alloc((size_t)8*64*256*80*4);   // 42 MB

  bf16_t* xb    = (bf16_t*)alloc(BSD*2);                  // -> x1b
  bf16_t* qkv   = (bf16_t*)alloc(3*BSD*2);                // qb | kb | vT contiguous
  bf16_t* h1    = (bf16_t*)alloc(BSD*4*2);                // 128 MB fp16 [16384][4096]
  float*  p2    = (float*)alloc(2*BSD*4);                 // 128 MB fp32 split-K partials

  bf16_t* x1b  = xb;
  bf16_t* qb   = qkv;
  bf16_t* kb   = qkv + BSD;
  bf16_t* vT   = qkv + 2*BSD;
  bf16_t* attn = qb;              // in-place over qb
  float*  y1   = (float*)d_out;   // fp32 x1 (LN1 out) lives in d_out until LN2

  constexpr int SH128 = (128+128)*64;      // 16384
  constexpr int SHQKV = 64*136*2;          // 17408 (>= core 16384)
  constexpr int SHFF1 = (128+256)*64;      // 24576 (128x256 tile)
  constexpr int SHKF  = 48384;
  constexpr int SHND  = 40192;

  // 1. converts / weight transposes
  cvt_kernel<<<(int)(BSD/1024), 256, 0, stream>>>(x, xb);
  tcvt3_kernel<<<dim3(16,48), 256, 0, stream>>>(wq, wk, wv, wqkvT);
  tcvt_kernel<<<dim3(16,16), 256, 0, stream>>>(wo, woT, 1024, 1024);
  tcvt_kernel<<<dim3(64,16), 256, 0, stream>>>(w1, w1T, 1024, 4096);
  tcvt_kernel<<<dim3(16,64), 256, 0, stream>>>(w2, w2T, 4096, 1024);
  cvt_kernel<<<16, 256, 0, stream>>>(omega, omg);

  // 2. merged QKV projection: [16384,1024] x [3072,1024]^T, 3072 blocks
  gemm_bt_kernel<128,128,2,2,4,4,E_QKV><<<dim3(128,24), 256, SHQKV, stream>>>(
      xb, D_, wqkvT, D_, qkv, D_, D_, nullptr, nullptr);

  // 3. sq (merged q+k)
  sq2_kernel<<<8192, 256, 0, stream>>>(qkv, sqq, sqk);

  // 4. fused phi(k)+kv aggregation (8 segments = 512 blocks), then reduce
  kv_fused<<<dim3(8,64), 256, SHKF, stream>>>(kb, sqk, omg, vT, kvp);
  kvred_kernel<<<dim3(4,64), 256, 0, stream>>>(kvp, kvT);

  // 5. fused phi(q)+num/den -> attn (in place over qb)
  numden_fused<<<dim3(64,64), 256, SHND, stream>>>(qb, sqq, omg, kvT, attn);

  // 6. out projection split-K=2 (2048 blocks, K=512/seg -> p2 partials),
  //    then fused reduce + residual(x) + LN1 -> y1 fp32 + x1b fp16
  gemm_bt_kernel<128,128,2,2,4,4,E_F32><<<dim3(128,16), 256, SH128, stream>>>(
      attn, D_, woT, D_, p2, D_, 512, nullptr, nullptr);
  ln1red_kernel<<<B_*S_, 256, 0, stream>>>(p2, x, ln1g, ln1b, y1, x1b);

  // 7. FFN1 128x256 tile / 8 waves (2048 blocks, +33% MFMA density vs 128^2);
  //    FFN2 split-K=2 (2048 blocks, K=2048/seg -> p2 partials)
  gemm_bt_kernel<128,256,2,4,4,4,E_GELU><<<dim3(128,16), 512, SHFF1, stream>>>(
      x1b, D_, w1T, D_, h1, FF_, D_, b1, nullptr);
  gemm_bt_kernel<128,128,2,2,4,4,E_F32><<<dim3(128,16), 256, SH128, stream>>>(
      h1, FF_, w2T, FF_, p2, D_, 2048, nullptr, nullptr);

  // 8. fused reduce + b2 + residual(y1) + LN2 -> output
  ln2red_kernel<<<B_*S_, 256, 0, stream>>>(p2, b2, y1, ln2g, ln2b, out);
}

// Round 12
// 1046.162 us; speedup vs baseline: 1.2119x; 1.0559x over previous
//
#include <hip/hip_runtime.h>
#include <cstdint>
#include <cstddef>

// ---------- problem constants ----------
#define B_   4
#define S_   4096
#define D_   1024
#define H_   16
#define KH   64
#define M_   256
#define FF_  4096

// fp16 compute path (same MFMA rate as bf16, lower quantization error)
typedef _Float16 bf16_t;
typedef _Float16 bf16x8 __attribute__((ext_vector_type(8)));
typedef _Float16 bf16x4 __attribute__((ext_vector_type(4)));
typedef float    f32x4  __attribute__((ext_vector_type(4)));

#define MFMA16(a,b,c) __builtin_amdgcn_mfma_f32_16x16x32_f16((a),(b),(c),0,0,0)

static constexpr size_t BSDc = (size_t)B_*S_*D_;   // 16,777,216 elements

// ---------- async global->LDS, 16B per lane ----------
__device__ __forceinline__ void async_copy16(const void* gp, void* lp) {
  auto g = reinterpret_cast<const __attribute__((address_space(1))) void*>(
      reinterpret_cast<uintptr_t>(gp));
  auto l = reinterpret_cast<__attribute__((address_space(3))) void*>(
      reinterpret_cast<uintptr_t>(lp));
  __builtin_amdgcn_global_load_lds(g, l, 16, 0, 0);
}

// ---------- generic B^T GEMM core (XOR bank-swizzled LDS tiles) ----------
template<int BM,int BN,int WROWS,int WCOLS,int WTM,int WTN>
__device__ __forceinline__ void gemm_bt_core(
    const bf16_t* __restrict__ At, int lda,
    const bf16_t* __restrict__ Bt, int ldb,
    int Kd, char* sm, f32x4 (&acc)[WTM][WTN])
{
  constexpr int NT = WROWS*WCOLS*64;
  static_assert(WROWS*WTM*16 == BM && WCOLS*WTN*16 == BN, "tile mismatch");
  const int t    = threadIdx.x;
  const int lane = t & 63;
  const int w    = t >> 6;
  const int wrow = w / WCOLS, wcol = w % WCOLS;
  const int l15  = lane & 15, quad = lane >> 4;
  char* As = sm;
  char* Bs = sm + BM*64;

#pragma unroll
  for (int i=0;i<WTM;i++)
#pragma unroll
    for (int j=0;j<WTN;j++)
      acc[i][j] = f32x4{0.f,0.f,0.f,0.f};

  constexpr int CA = BM*4;
  static_assert(CA % NT == 0, "A staging must be whole issues");
  constexpr int AI    = CA / NT;
  constexpr int BFULL = (BN*4) / NT;
  constexpr int BREM  = (BN*4) % NT;

  for (int kk = 0; kk < Kd; kk += 32) {
    __syncthreads();
#pragma unroll
    for (int ii=0; ii<AI; ii++) {
      int c  = ii*NT + t;
      int cw = ii*NT + (t & ~63);
      int r  = c >> 2;
      int js = (c & 3) ^ ((r >> 1) & 3);         // swizzled source chunk
      async_copy16(At + (size_t)r*lda + kk + js*8, As + (size_t)cw*16);
    }
#pragma unroll
    for (int ii=0; ii<BFULL; ii++) {
      int c  = ii*NT + t;
      int cw = ii*NT + (t & ~63);
      int r  = c >> 2;
      int js = (c & 3) ^ ((r >> 1) & 3);
      async_copy16(Bt + (size_t)r*ldb + kk + js*8, Bs + (size_t)cw*16);
    }
    if constexpr (BREM != 0) {
      if (t < BREM) {
        int c  = BFULL*NT + t;
        int cw = BFULL*NT + (t & ~63);
        int r  = c >> 2;
        int js = (c & 3) ^ ((r >> 1) & 3);
        async_copy16(Bt + (size_t)r*ldb + kk + js*8, Bs + (size_t)cw*16);
      }
    }
    __syncthreads();

    bf16x8 af[WTM], bv[WTN];
#pragma unroll
    for (int mi=0; mi<WTM; mi++) {
      int row = wrow*(WTM*16) + mi*16 + l15;
      int sw  = quad ^ ((row >> 1) & 3);
      af[mi] = *(const bf16x8*)(As + row*64 + sw*16);
    }
#pragma unroll
    for (int nj=0; nj<WTN; nj++) {
      int rn = wcol*(WTN*16) + nj*16 + l15;
      int sw = quad ^ ((rn >> 1) & 3);
      bv[nj] = *(const bf16x8*)(Bs + rn*64 + sw*16);
    }
#pragma unroll
    for (int mi=0; mi<WTM; mi++)
#pragma unroll
      for (int nj=0; nj<WTN; nj++)
        acc[mi][nj] = MFMA16(af[mi], bv[nj], acc[mi][nj]);
  }
}

// ---------- epilogue variants ----------
enum { E_BF16 = 0, E_GELU = 2, E_RESF32 = 3, E_QKV = 5, E_F32 = 6 };

// exact-GELU via A&S 7.1.26 erf approximation (|err| ~1.5e-7).
__device__ __forceinline__ float gelu_f(float v) {
  float u  = v * 0.70710678118654752f;
  float au = fabsf(u);
  float tt = __builtin_amdgcn_rcpf(1.0f + 0.3275911f*au);
  float poly = tt*(0.254829592f + tt*(-0.284496736f + tt*(1.421413741f +
               tt*(-1.453152027f + tt*1.061405429f))));
  float er = 1.0f - poly*__expf(-au*au);
  er = __builtin_copysignf(er, u);
  return 0.5f * v * (1.0f + er);
}

template<int BM,int BN,int WROWS,int WCOLS,int WTM,int WTN,int EPI>
__global__ __launch_bounds__(WROWS*WCOLS*64)
void gemm_bt_kernel(const bf16_t* __restrict__ A, int lda,
                    const bf16_t* __restrict__ Bt, int ldb,
                    void* __restrict__ C, int ldc,
                    int Kd, const float* __restrict__ bias, const float* __restrict__ res)
{
  extern __shared__ float4 smem4[];
  char* sm = (char*)smem4;

  // XCD-aware bijective swizzle (T1): each XCD owns a contiguous work chunk.
  // E_F32 (split-K) uses a bx-MAJOR linearization so the blocks sharing one
  // A-panel (all by for a given bx) are adjacent in dispatch order -> A-panel
  // fetched ~once per XCD (R10: FETCH was 4.4x ideal with by-major order).
  const int nbx = gridDim.x;
  const int nwg = nbx * gridDim.y;
  int bx, by;
  {
    int orig;
    if constexpr (EPI == E_F32) orig = blockIdx.x * gridDim.y + blockIdx.y;
    else                        orig = blockIdx.y * nbx + blockIdx.x;
    if ((nwg & 7) == 0) {
      int swz = (orig & 7) * (nwg >> 3) + (orig >> 3);
      if constexpr (EPI == E_F32) { bx = swz / gridDim.y; by = swz % gridDim.y; }
      else                        { bx = swz % nbx;       by = swz / nbx; }
    } else { bx = blockIdx.x; by = blockIdx.y; }
  }

  // E_F32 = split-K=2 partials: upper half of by-range selects K-segment 1.
  int seg = 0;
  if constexpr (EPI == E_F32) {
    const int half = gridDim.y >> 1;
    if (by >= half) { seg = 1; by -= half; }
  }
  const int koff = seg * Kd;

  const bf16_t* At  = A  + (size_t)bx*BM*lda + koff;
  const bf16_t* Bt2 = Bt + (size_t)by*BN*ldb + koff;
  f32x4 acc[WTM][WTN];
  gemm_bt_core<BM,BN,WROWS,WCOLS,WTM,WTN>(At, lda, Bt2, ldb, Kd, sm, acc);

  const int t=threadIdx.x, lane=t&63, w=t>>6;
  const int wrow=w/WCOLS, wcol=w%WCOLS, l15=lane&15, quad=lane>>4;

  if constexpr (EPI == E_QKV) {
    // merged QKV: by 0..7 -> q, 8..15 -> k, 16..23 -> vT (transposed)
    const int yb = by;
    bf16_t* base = (bf16_t*)C;              // qb; kb = +BSD; vT = +2*BSD
    if (yb < 16) {
      bf16_t* dst = base + (size_t)(yb >> 3) * BSDc;
      const size_t colbase = (size_t)(yb & 7) * 128;
#pragma unroll
      for (int mi=0; mi<WTM; mi++)
#pragma unroll
        for (int nj=0; nj<WTN; nj++) {
          size_t col = colbase + wcol*64 + nj*16 + l15;
#pragma unroll
          for (int reg=0; reg<4; reg++) {
            size_t row = (size_t)bx*128 + wrow*64 + mi*16 + quad*4 + reg;
            dst[row*D_ + col] = (bf16_t)acc[mi][nj][reg];
          }
        }
    } else {
      bf16_t* vT = base + 2*BSDc;
      bf16_t* ldsT = (bf16_t*)sm;           // [64 cols][136 rows]
      const int b  = (bx*128) >> 12;
      const int s0 = (bx*128) & 4095;
#pragma unroll
      for (int half2=0; half2<2; half2++) {
        __syncthreads();                    // core LDS reads done / prev drain done
        if (wcol == half2) {
#pragma unroll
          for (int mi=0; mi<WTM; mi++)
#pragma unroll
            for (int nj=0; nj<WTN; nj++)
#pragma unroll
              for (int reg=0; reg<4; reg++) {
                int col = nj*16 + l15;
                int row = wrow*64 + mi*16 + quad*4 + reg;
                ldsT[col*136 + row] = (bf16_t)acc[mi][nj][reg];
              }
        }
        __syncthreads();
        // 64 cols x 16 chunks = 1024 -> 4 passes
#pragma unroll
        for (int pass=0; pass<4; pass++) {
          int idx = pass*256 + t;
          int col = idx >> 4, ch = idx & 15;
          int d = (yb-16)*128 + half2*64 + col;
          int hh = d >> 6, cc = d & 63;
          bf16x8 v = *(const bf16x8*)(ldsT + col*136 + ch*8);
          *(bf16x8*)(vT + (((size_t)b*H_ + hh)*KH + cc)*S_ + s0 + ch*8) = v;
        }
      }
    }
    return;
  }

#pragma unroll
  for (int mi=0; mi<WTM; mi++) {
#pragma unroll
    for (int nj=0; nj<WTN; nj++) {
      size_t col = (size_t)by*BN + wcol*(WTN*16) + nj*16 + l15;
#pragma unroll
      for (int reg=0; reg<4; reg++) {
        size_t row = (size_t)bx*BM + wrow*(WTM*16) + mi*16 + quad*4 + reg;
        float v = acc[mi][nj][reg];
        if constexpr (EPI == E_BF16) {
          ((bf16_t*)C)[row*ldc + col] = (bf16_t)v;
        } else if constexpr (EPI == E_GELU) {
          v += bias[col];
          v = gelu_f(v);
          ((bf16_t*)C)[row*ldc + col] = (bf16_t)v;
        } else if constexpr (EPI == E_F32) {
          float* dst = (float*)C + (size_t)seg * ((size_t)gridDim.x * BM) * ldc;
          dst[row*ldc + col] = v;
        } else {  // E_RESF32
          if (bias) v += bias[col];
          v += res[row*(size_t)ldc + col];
          ((float*)C)[row*ldc + col] = v;
        }
      }
    }
  }
}

// ---------- fused phi(k) + kv aggregation ----------
// grid: (8 seg, 64 bh).  kvp fp32 [seg][bh][256 m][80 c]
__global__ __launch_bounds__(256)
void kv_fused(const bf16_t* __restrict__ kb, const float* __restrict__ sqk,
              const bf16_t* __restrict__ omg, const bf16_t* __restrict__ vT,
              float* __restrict__ kvp)
{
  extern __shared__ float4 smem4[];
  char* sm = (char*)smem4;
  bf16_t* PT   = (bf16_t*)sm;             // [256 m][72] (overlaps core As/Bs)
  bf16_t* Vs   = (bf16_t*)(sm + 36864);   // [80 c][64 s] (128B rows, 8 chunks, swizzled)
  float*  stab = (float*)(sm + 47104);    // 256
  float*  comb = (float*)(sm + 48128);    // 64
  const int g = blockIdx.x, bh = blockIdx.y, b = bh >> 4, h = bh & 15;
  const int t=threadIdx.x, lane=t&63, w=t>>6, l15=lane&15, quad=lane>>4;
  const float scale = 0.35355339059327379f;   // 64^-0.25

#pragma unroll
  for (int j=0;j<4;j++){
    int idx = j*256 + t;
    int r = 64 + (idx>>6), s = idx & 63;
    Vs[r*64 + s] = (bf16_t)((r==64) ? 1.0f : 0.0f);
  }

  f32x4 acc2[4][5];
#pragma unroll
  for (int i=0;i<4;i++)
#pragma unroll
    for (int j=0;j<5;j++) acc2[i][j] = f32x4{0.f,0.f,0.f,0.f};

  for (int ch=0; ch<8; ch++) {
    const int s0 = g*512 + ch*64;
    const bf16_t* At = kb + ((size_t)b*S_ + s0)*D_ + h*KH;
    f32x4 acc[4][4];
    gemm_bt_core<64,256,1,4,4,4>(At, D_, omg, KH, KH, sm, acc);

#pragma unroll
    for (int mi=0; mi<4; mi++) {
#pragma unroll
      for (int reg=0; reg<4; reg++) {
        float mx = fmaxf(fmaxf(acc[mi][0][reg], acc[mi][1][reg]),
                         fmaxf(acc[mi][2][reg], acc[mi][3][reg]));
#pragma unroll
        for (int off=1; off<16; off<<=1) mx = fmaxf(mx, __shfl_xor(mx, off, 64));
        if (l15 == 0) stab[w*64 + mi*16 + quad*4 + reg] = mx;
      }
    }
    __syncthreads();
    if (t < 64) {
      float m4 = fmaxf(fmaxf(stab[t], stab[64+t]), fmaxf(stab[128+t], stab[192+t]));
      comb[t] = m4*scale + sqk[(size_t)bh*S_ + s0 + t];
    }
    __syncthreads();
#pragma unroll
    for (int mi=0; mi<4; mi++)
#pragma unroll
      for (int nj=0; nj<4; nj++)
#pragma unroll
        for (int reg=0; reg<4; reg++) {
          int row = mi*16 + quad*4 + reg;          // s-local
          int col = w*64 + nj*16 + l15;            // m
          float p = __expf(scale*acc[mi][nj][reg] - comb[row]) * 0.0625f + 1e-6f;
          PT[col*72 + row] = (bf16_t)p;
        }
#pragma unroll
    for (int ii=0; ii<2; ii++) {
      int c2 = ii*256 + t;
      int cw = ii*256 + (t & ~63);
      int r  = c2 >> 3;
      int js = (c2 & 7) ^ (r & 7);
      async_copy16(vT + ((size_t)bh*KH + r)*S_ + s0 + js*8,
                   (char*)Vs + (size_t)cw*16);
    }
    __syncthreads();
#pragma unroll
    for (int ks=0; ks<2; ks++) {
      bf16x8 af[4];
#pragma unroll
      for (int mi=0; mi<4; mi++)
        af[mi] = *(const bf16x8*)(PT + (w*64 + mi*16 + l15)*72 + ks*32 + quad*8);
#pragma unroll
      for (int nj=0; nj<5; nj++) {
        int rr = nj*16 + l15;
        int slot = (ks*4 + quad) ^ (rr & 7);
        bf16x8 bv = *(const bf16x8*)(Vs + rr*64 + slot*8);
#pragma unroll
        for (int mi=0; mi<4; mi++)
          acc2[mi][nj] = MFMA16(af[mi], bv, acc2[mi][nj]);
      }
    }
  }

#pragma unroll
  for (int mi=0; mi<4; mi++)
#pragma unroll
    for (int nj=0; nj<5; nj++)
#pragma unroll
      for (int reg=0; reg<4; reg++) {
        int m = w*64 + mi*16 + quad*4 + reg;
        int c = nj*16 + l15;
        kvp[(((size_t)g*64 + bh)*256 + m)*80 + c] = acc2[mi][nj][reg];
      }
}

// reduce 8 segments -> kvT[bh][c][m] fp16; grid (4 mblk, 64 bh)
__global__ __launch_bounds__(256)
void kvred_kernel(const float* __restrict__ kvp, bf16_t* __restrict__ kvT)
{
  __shared__ float accs[64*81];
  const int mb = blockIdx.x, bh = blockIdx.y, t = threadIdx.x;
  const int m0 = mb*64;
  float r[20];
#pragma unroll
  for (int i=0;i<20;i++) r[i] = 0.f;
  for (int g2=0; g2<8; g2++) {
    const float* p = kvp + (((size_t)g2*64 + bh)*256 + m0)*80;
#pragma unroll
    for (int i=0;i<20;i++) r[i] += p[i*256 + t];
  }
#pragma unroll
  for (int i=0;i<20;i++) {
    int idx = i*256 + t;           // = mloc*80 + c
    int ml = idx / 80, cc = idx - ml*80;
    accs[ml*81 + cc] = r[i];
  }
  __syncthreads();
  bf16_t* o = kvT + (size_t)bh*(80*M_);
#pragma unroll
  for (int i=0;i<20;i++) {
    int idx2 = i*256 + t;          // = c*64 + mloc
    int c = idx2 >> 6, ml = idx2 & 63;
    o[(size_t)c*M_ + m0 + ml] = (bf16_t)accs[ml*81 + c];
  }
}

// ---------- fused phi(q) + num/den ----------
__global__ __launch_bounds__(256)
void numden_fused(const bf16_t* __restrict__ qb, const float* __restrict__ sqv,
                  const bf16_t* __restrict__ omg, const bf16_t* __restrict__ kvT,
                  bf16_t* __restrict__ attn)
{
  extern __shared__ float4 smem4[];
  char* sm = (char*)smem4;
  bf16_t* P    = (bf16_t*)sm;             // [64 s][264 m] (overlaps core As/Bs)
  char*   Bs2  = sm + 33792;              // 80 rows x 64B (4 chunks, swizzled)
  float*  stab = (float*)(sm + 38912);
  float*  comb = (float*)(sm + 39936);
  const int bh = blockIdx.y, b = bh >> 4, h = bh & 15;
  const int s0 = blockIdx.x * 64;
  const bf16_t* At = qb + ((size_t)b*S_ + s0)*D_ + h*KH;
  f32x4 acc[4][4];
  gemm_bt_core<64,256,1,4,4,4>(At, D_, omg, KH, KH, sm, acc);

  const int t=threadIdx.x, lane=t&63, w=t>>6, l15=lane&15, quad=lane>>4;
  const float scale = 0.35355339059327379f;

#pragma unroll
  for (int mi=0; mi<4; mi++) {
#pragma unroll
    for (int reg=0; reg<4; reg++) {
      float mx = fmaxf(fmaxf(acc[mi][0][reg], acc[mi][1][reg]),
                       fmaxf(acc[mi][2][reg], acc[mi][3][reg]));
#pragma unroll
      for (int off=1; off<16; off<<=1) mx = fmaxf(mx, __shfl_xor(mx, off, 64));
      if (l15 == 0) stab[w*64 + mi*16 + quad*4 + reg] = mx;
    }
  }
  __syncthreads();
  if (t < 64) {
    float m4 = fmaxf(fmaxf(stab[t], stab[64+t]), fmaxf(stab[128+t], stab[192+t]));
    comb[t] = m4*scale + sqv[(size_t)bh*S_ + s0 + t];
  }
  __syncthreads();
#pragma unroll
  for (int mi=0; mi<4; mi++)
#pragma unroll
    for (int nj=0; nj<4; nj++)
#pragma unroll
      for (int reg=0; reg<4; reg++) {
        int row = mi*16 + quad*4 + reg;
        int col = w*64 + nj*16 + l15;
        float p = __expf(scale*acc[mi][nj][reg] - comb[row]) * 0.0625f + 1e-6f;
        P[row*264 + col] = (bf16_t)p;
      }

  const bf16_t* Bt = kvT + (size_t)bh*80*M_;
  f32x4 acc2[5];
#pragma unroll
  for (int j=0;j<5;j++) acc2[j] = f32x4{0.f,0.f,0.f,0.f};

  for (int kk = 0; kk < 256; kk += 32) {
    __syncthreads();
    {
      int c = t, cw = (t & ~63);
      int r = c >> 2;
      int js = (c & 3) ^ ((r >> 1) & 3);
      async_copy16(Bt + (size_t)r*M_ + kk + js*8, Bs2 + (size_t)cw*16);
    }
    if (t < 64) {
      int c = 256 + t;
      int r = c >> 2;
      int js = (c & 3) ^ ((r >> 1) & 3);
      async_copy16(Bt + (size_t)r*M_ + kk + js*8, Bs2 + (size_t)256*16);
    }
    __syncthreads();
    bf16x8 af = *(const bf16x8*)(P + (w*16 + l15)*264 + kk + quad*8);
#pragma unroll
    for (int nj=0; nj<5; nj++) {
      int rn = nj*16 + l15;
      int sw = quad ^ ((rn >> 1) & 3);
      bf16x8 bv = *(const bf16x8*)(Bs2 + rn*64 + sw*16);
      acc2[nj] = MFMA16(af, bv, acc2[nj]);
    }
  }

#pragma unroll
  for (int reg=0; reg<4; reg++) {
    float den = __shfl(acc2[4][reg], (lane & 48), 64);
    int row = w*16 + quad*4 + reg;
#pragma unroll
    for (int nj=0; nj<4; nj++) {
      float v = acc2[nj][reg] / den;
      attn[((size_t)b*S_ + s0 + row)*D_ + h*KH + nj*16 + l15] = (bf16_t)v;
    }
  }
}

// ---------- small kernels ----------
__global__ __launch_bounds__(256)
void cvt_kernel(const float* __restrict__ in, bf16_t* __restrict__ out)
{
  const size_t i = ((size_t)blockIdx.x*256 + threadIdx.x)*4;
  const float4 a = *(const float4*)(in + i);
  bf16x4 o; o[0]=(bf16_t)a.x; o[1]=(bf16_t)a.y; o[2]=(bf16_t)a.z; o[3]=(bf16_t)a.w;
  *(bf16x4*)(out + i) = o;
}

__global__ __launch_bounds__(256)
void tcvt_kernel(const float* __restrict__ in, bf16_t* __restrict__ out, int R, int C)
{
  __shared__ float tile[64][65];
  const int r0 = blockIdx.y*64, c0 = blockIdx.x*64;
  const int tx = threadIdx.x & 63, ty = threadIdx.x >> 6;
  for (int i=ty; i<64; i+=4) tile[i][tx] = in[(size_t)(r0+i)*C + c0 + tx];
  __syncthreads();
  for (int i=ty; i<64; i+=4) out[(size_t)(c0+i)*R + r0 + tx] = (bf16_t)tile[tx][i];
}

// merged wq/wk/wv transpose (1024x1024 each) -> stacked wqkvT; grid (16, 48)
__global__ __launch_bounds__(256)
void tcvt3_kernel(const float* __restrict__ wqp, const float* __restrict__ wkp,
                  const float* __restrict__ wvp, bf16_t* __restrict__ out)
{
  __shared__ float tile[64][65];
  const int sel = blockIdx.y >> 4, ry = blockIdx.y & 15;
  const float* in = (sel==0) ? wqp : (sel==1) ? wkp : wvp;
  bf16_t* o = out + (size_t)sel*D_*D_;
  const int r0 = ry*64, c0 = blockIdx.x*64;
  const int tx = threadIdx.x & 63, ty = threadIdx.x >> 6;
  for (int i=ty; i<64; i+=4) tile[i][tx] = in[(size_t)(r0+i)*D_ + c0 + tx];
  __syncthreads();
  for (int i=ty; i<64; i+=4) o[(size_t)(c0+i)*D_ + r0 + tx] = (bf16_t)tile[tx][i];
}

// merged sq for q and k: blocks 0..4095 -> qb rows, 4096..8191 -> kb rows
__global__ __launch_bounds__(256)
void sq2_kernel(const bf16_t* __restrict__ qkv, float* __restrict__ sqq,
                float* __restrict__ sqk)
{
  const int bi   = blockIdx.x;
  const int ksel = bi >> 12;
  const int i    = ((bi & 4095)<<2) + (threadIdx.x>>6);
  const int lane = threadIdx.x & 63;
  const bf16_t* row = qkv + (size_t)ksel*BSDc + (size_t)i*D_ + lane*16;
  bf16x8 v0 = *(const bf16x8*)row;
  bf16x8 v1 = *(const bf16x8*)(row + 8);
  float s = 0.f;
#pragma unroll
  for (int j=0;j<8;j++){ float a=(float)v0[j], c=(float)v1[j]; s += a*a + c*c; }
  s += __shfl_xor(s, 1, 64);
  s += __shfl_xor(s, 2, 64);
  if ((lane&3)==0) {
    const int h = lane>>2, b = i>>12, ss = i & 4095;
    float* sq = ksel ? sqk : sqq;
    sq[((size_t)b*H_ + h)*S_ + ss] = 0.0625f * s;
  }
}

// fused split-K reduce + residual + LN1 + fp16 copy; one block per row.
// a = p2[0][row] + p2[1][row] + res[row] (res = original x, no bias on out-proj)
// outf = LN1(a) fp32; outb = same in fp16.
__global__ __launch_bounds__(256)
void ln1red_kernel(const float* __restrict__ p2, const float* __restrict__ res,
                   const float* __restrict__ g, const float* __restrict__ bt,
                   float* __restrict__ outf, bf16_t* __restrict__ outb)
{
  __shared__ float rs[4], rs2[4];
  const size_t row = blockIdx.x;
  const int t = threadIdx.x;
  const float4 a0 = ((const float4*)(p2 + row*D_))[t];
  const float4 a1 = ((const float4*)(p2 + BSDc + row*D_))[t];
  const float4 rr = ((const float4*)(res + row*D_))[t];
  float4 a;
  a.x = a0.x + a1.x + rr.x;
  a.y = a0.y + a1.y + rr.y;
  a.z = a0.z + a1.z + rr.z;
  a.w = a0.w + a1.w + rr.w;
  float s  = a.x+a.y+a.z+a.w;
  float s2 = a.x*a.x + a.y*a.y + a.z*a.z + a.w*a.w;
#pragma unroll
  for (int off=32; off; off>>=1) { s += __shfl_xor(s, off, 64); s2 += __shfl_xor(s2, off, 64); }
  if ((t&63)==0) { rs[t>>6]=s; rs2[t>>6]=s2; }
  __syncthreads();
  const float S1 = rs[0]+rs[1]+rs[2]+rs[3];
  const float S2 = rs2[0]+rs2[1]+rs2[2]+rs2[3];
  const float mu   = S1 * (1.f/1024.f);
  const float rstd = rsqrtf(S2 * (1.f/1024.f) - mu*mu + 1e-6f);
  const float4 gg = ((const float4*)g)[t];
  const float4 bb = ((const float4*)bt)[t];
  float4 oo;
  oo.x = (a.x-mu)*rstd*gg.x + bb.x;
  oo.y = (a.y-mu)*rstd*gg.y + bb.y;
  oo.z = (a.z-mu)*rstd*gg.z + bb.z;
  oo.w = (a.w-mu)*rstd*gg.w + bb.w;
  ((float4*)(outf + row*D_))[t] = oo;
  bf16x4 ob; ob[0]=(bf16_t)oo.x; ob[1]=(bf16_t)oo.y; ob[2]=(bf16_t)oo.z; ob[3]=(bf16_t)oo.w;
  *(bf16x4*)(outb + row*D_ + t*4) = ob;
}

// fused split-K reduce + bias + residual + LN2; one block per row.
// a = p2[0][row] + p2[1][row] + b2 + y1[row]; out = LN(a). In-place-per-row
// safe vs res==out (all reads precede the row's writes).
__global__ __launch_bounds__(256)
void ln2red_kernel(const float* __restrict__ p2, const float* __restrict__ bias,
                   const float* __restrict__ res, const float* __restrict__ g,
                   const float* __restrict__ bt, float* __restrict__ outp)
{
  __shared__ float rs[4], rs2[4];
  const size_t row = blockIdx.x;
  const int t = threadIdx.x;
  const float4 a0 = ((const float4*)(p2 + row*D_))[t];
  const float4 a1 = ((const float4*)(p2 + BSDc + row*D_))[t];
  const float4 bb2 = ((const float4*)bias)[t];
  const float4 rr = ((const float4*)(res + row*D_))[t];
  float4 a;
  a.x = a0.x + a1.x + bb2.x + rr.x;
  a.y = a0.y + a1.y + bb2.y + rr.y;
  a.z = a0.z + a1.z + bb2.z + rr.z;
  a.w = a0.w + a1.w + bb2.w + rr.w;
  float s  = a.x+a.y+a.z+a.w;
  float s2 = a.x*a.x + a.y*a.y + a.z*a.z + a.w*a.w;
#pragma unroll
  for (int off=32; off; off>>=1) { s += __shfl_xor(s, off, 64); s2 += __shfl_xor(s2, off, 64); }
  if ((t&63)==0) { rs[t>>6]=s; rs2[t>>6]=s2; }
  __syncthreads();
  const float S1 = rs[0]+rs[1]+rs[2]+rs[3];
  const float S2 = rs2[0]+rs2[1]+rs2[2]+rs2[3];
  const float mu   = S1 * (1.f/1024.f);
  const float rstd = rsqrtf(S2 * (1.f/1024.f) - mu*mu + 1e-6f);
  const float4 gg = ((const float4*)g)[t];
  const float4 bb = ((const float4*)bt)[t];
  float4 oo;
  oo.x = (a.x-mu)*rstd*gg.x + bb.x;
  oo.y = (a.y-mu)*rstd*gg.y + bb.y;
  oo.z = (a.z-mu)*rstd*gg.z + bb.z;
  oo.w = (a.w-mu)*rstd*gg.w + bb.w;
  ((float4*)(outp + row*D_))[t] = oo;
}

// ---------- load-time fallback workspace ----------
// Alloc-list sum = 474.5 MB; 480 MB gives headroom + alignment pad.
static const size_t NEED = 480000000;
static void* g_fb = nullptr;
struct FbInit {
  FbInit() { if (hipMalloc(&g_fb, NEED) != hipSuccess) g_fb = nullptr; }
};
static FbInit g_fbinit;

// ---------- launcher ----------
extern "C" void kernel_launch(void* const* d_in, const int* in_sizes, int n_in,
                              void* d_out, int out_size, void* d_ws, size_t ws_size,
                              hipStream_t stream)
{
  (void)in_sizes; (void)n_in; (void)out_size;
  const float* x     = (const float*)d_in[0];
  const float* wq    = (const float*)d_in[1];
  const float* wk    = (const float*)d_in[2];
  const float* wv    = (const float*)d_in[3];
  const float* wo    = (const float*)d_in[4];
  const float* omega = (const float*)d_in[5];
  const float* ln1g  = (const float*)d_in[6];
  const float* ln1b  = (const float*)d_in[7];
  const float* w1    = (const float*)d_in[8];
  const float* b1    = (const float*)d_in[9];
  const float* w2    = (const float*)d_in[10];
  const float* b2    = (const float*)d_in[11];
  const float* ln2g  = (const float*)d_in[12];
  const float* ln2b  = (const float*)d_in[13];
  float* out = (float*)d_out;

  char* ws = (ws_size >= NEED) ? (char*)d_ws : (char*)g_fb;
  if (!ws) return;

  size_t o = 0;
  auto alloc = [&](size_t bytes) -> char* {
    char* p = ws + o; o += (bytes + 255) & ~(size_t)255; return p;
  };
  const size_t BSD = BSDc;

  bf16_t* wqkvT = (bf16_t*)alloc((size_t)3*D_*D_*2);      // stacked q|k|v B^T
  bf16_t* woT   = (bf16_t*)alloc((size_t)D_*D_*2);
  bf16_t* w1T   = (bf16_t*)alloc((size_t)D_*FF_*2);
  bf16_t* w2T   = (bf16_t*)alloc((size_t)D_*FF_*2);
  bf16_t* omg   = (bf16_t*)alloc((size_t)M_*KH*2);
  float*  sqq   = (float*)alloc((size_t)B_*H_*S_*4);
  float*  sqk   = (float*)alloc((size_t)B_*H_*S_*4);
  bf16_t* kvT   = (bf16_t*)alloc((size_t)B_*H_*80*M_*2);
  float*  kvp   = (float*)alloc((size_t)8*64*256*80*4);   // 42 MB

  bf16_t* xb    = (bf16_t*)alloc(BSD*2);                  // -> x1b
  bf16_t* qkv   = (bf16_t*)alloc(3*BSD*2);                // qb | kb | vT contiguous
  bf16_t* h1    = (bf16_t*)alloc(BSD*4*2);                // 128 MB fp16 [16384][4096]
  float*  p2    = (float*)alloc(2*BSD*4);                 // 128 MB fp32 split-K partials

  bf16_t* x1b  = xb;
  bf16_t* qb   = qkv;
  bf16_t* kb   = qkv + BSD;
  bf16_t* vT   = qkv + 2*BSD;
  bf16_t* attn = qb;              // in-place over qb
  float*  y1   = (float*)d_out;   // fp32 x1 (LN1 out) lives in d_out until LN2

  constexpr int SH128 = (128+128)*64;      // 16384
  constexpr int SHQKV = 64*136*2;          // 17408 (>= core 16384)
  constexpr int SHFF  = (128+256)*64;      // 24576 (128x256 tile)
  constexpr int SHKF  = 48384;
  constexpr int SHND  = 40192;

  // 1. converts / weight transposes
  cvt_kernel<<<(int)(BSD/1024), 256, 0, stream>>>(x, xb);
  tcvt3_kernel<<<dim3(16,48), 256, 0, stream>>>(wq, wk, wv, wqkvT);
  tcvt_kernel<<<dim3(16,16), 256, 0, stream>>>(wo, woT, 1024, 1024);
  tcvt_kernel<<<dim3(64,16), 256, 0, stream>>>(w1, w1T, 1024, 4096);
  tcvt_kernel<<<dim3(16,64), 256, 0, stream>>>(w2, w2T, 4096, 1024);
  cvt_kernel<<<16, 256, 0, stream>>>(omega, omg);

  // 2. merged QKV projection: [16384,1024] x [3072,1024]^T, 3072 blocks
  gemm_bt_kernel<128,128,2,2,4,4,E_QKV><<<dim3(128,24), 256, SHQKV, stream>>>(
      xb, D_, wqkvT, D_, qkv, D_, D_, nullptr, nullptr);

  // 3. sq (merged q+k)
  sq2_kernel<<<8192, 256, 0, stream>>>(qkv, sqq, sqk);

  // 4. fused phi(k)+kv aggregation (8 segments = 512 blocks), then reduce
  kv_fused<<<dim3(8,64), 256, SHKF, stream>>>(kb, sqk, omg, vT, kvp);
  kvred_kernel<<<dim3(4,64), 256, 0, stream>>>(kvp, kvT);

  // 5. fused phi(q)+num/den -> attn (in place over qb)
  numden_fused<<<dim3(64,64), 256, SHND, stream>>>(qb, sqq, omg, kvT, attn);

  // 6. out projection split-K=2 (2048 blocks, K=512/seg -> p2 partials),
  //    then fused reduce + residual(x) + LN1 -> y1 fp32 + x1b fp16
  gemm_bt_kernel<128,128,2,2,4,4,E_F32><<<dim3(128,16), 256, SH128, stream>>>(
      attn, D_, woT, D_, p2, D_, 512, nullptr, nullptr);
  ln1red_kernel<<<B_*S_, 256, 0, stream>>>(p2, x, ln1g, ln1b, y1, x1b);

  // 7. FFN1 128x256 tile / 8 waves (2048 blocks);
  //    FFN2 128x256 tile split-K=2 (1024 blocks, K=2048/seg, bx-major order)
  gemm_bt_kernel<128,256,2,4,4,4,E_GELU><<<dim3(128,16), 512, SHFF, stream>>>(
      x1b, D_, w1T, D_, h1, FF_, D_, b1, nullptr);
  gemm_bt_kernel<128,256,2,4,4,4,E_F32><<<dim3(128,8), 512, SHFF, stream>>>(
      h1, FF_, w2T, FF_, p2, D_, 2048, nullptr, nullptr);

  // 8. fused reduce + b2 + residual(y1) + LN2 -> output
  ln2red_kernel<<<B_*S_, 256, 0, stream>>>(p2, b2, y1, ln2g, ln2b, out);
}

// Round 13
// 1006.067 us; speedup vs baseline: 1.2602x; 1.0399x over previous
//
#include <hip/hip_runtime.h>
#include <cstdint>
#include <cstddef>

// ---------- problem constants ----------
#define B_   4
#define S_   4096
#define D_   1024
#define H_   16
#define KH   64
#define M_   256
#define FF_  4096

// fp16 compute path (same MFMA rate as bf16, lower quantization error)
typedef _Float16 bf16_t;
typedef _Float16 bf16x8 __attribute__((ext_vector_type(8)));
typedef _Float16 bf16x4 __attribute__((ext_vector_type(4)));
typedef float    f32x4  __attribute__((ext_vector_type(4)));

#define MFMA16(a,b,c) __builtin_amdgcn_mfma_f32_16x16x32_f16((a),(b),(c),0,0,0)

static constexpr size_t BSDc = (size_t)B_*S_*D_;   // 16,777,216 elements

// ---------- async global->LDS, 16B per lane ----------
__device__ __forceinline__ void async_copy16(const void* gp, void* lp) {
  auto g = reinterpret_cast<const __attribute__((address_space(1))) void*>(
      reinterpret_cast<uintptr_t>(gp));
  auto l = reinterpret_cast<__attribute__((address_space(3))) void*>(
      reinterpret_cast<uintptr_t>(lp));
  __builtin_amdgcn_global_load_lds(g, l, 16, 0, 0);
}

// ---------- generic B^T GEMM core (XOR bank-swizzled LDS tiles) ----------
// Single-buffer variant (used by attention kernels whose LDS overlays the
// core scratch; unchanged, measured-good).
template<int BM,int BN,int WROWS,int WCOLS,int WTM,int WTN>
__device__ __forceinline__ void gemm_bt_core(
    const bf16_t* __restrict__ At, int lda,
    const bf16_t* __restrict__ Bt, int ldb,
    int Kd, char* sm, f32x4 (&acc)[WTM][WTN])
{
  constexpr int NT = WROWS*WCOLS*64;
  static_assert(WROWS*WTM*16 == BM && WCOLS*WTN*16 == BN, "tile mismatch");
  const int t    = threadIdx.x;
  const int lane = t & 63;
  const int w    = t >> 6;
  const int wrow = w / WCOLS, wcol = w % WCOLS;
  const int l15  = lane & 15, quad = lane >> 4;
  char* As = sm;
  char* Bs = sm + BM*64;

#pragma unroll
  for (int i=0;i<WTM;i++)
#pragma unroll
    for (int j=0;j<WTN;j++)
      acc[i][j] = f32x4{0.f,0.f,0.f,0.f};

  constexpr int CA = BM*4;
  static_assert(CA % NT == 0, "A staging must be whole issues");
  constexpr int AI    = CA / NT;
  constexpr int BFULL = (BN*4) / NT;
  constexpr int BREM  = (BN*4) % NT;

  for (int kk = 0; kk < Kd; kk += 32) {
    __syncthreads();
#pragma unroll
    for (int ii=0; ii<AI; ii++) {
      int c  = ii*NT + t;
      int cw = ii*NT + (t & ~63);
      int r  = c >> 2;
      int js = (c & 3) ^ ((r >> 1) & 3);         // swizzled source chunk
      async_copy16(At + (size_t)r*lda + kk + js*8, As + (size_t)cw*16);
    }
#pragma unroll
    for (int ii=0; ii<BFULL; ii++) {
      int c  = ii*NT + t;
      int cw = ii*NT + (t & ~63);
      int r  = c >> 2;
      int js = (c & 3) ^ ((r >> 1) & 3);
      async_copy16(Bt + (size_t)r*ldb + kk + js*8, Bs + (size_t)cw*16);
    }
    if constexpr (BREM != 0) {
      if (t < BREM) {
        int c  = BFULL*NT + t;
        int cw = BFULL*NT + (t & ~63);
        int r  = c >> 2;
        int js = (c & 3) ^ ((r >> 1) & 3);
        async_copy16(Bt + (size_t)r*ldb + kk + js*8, Bs + (size_t)cw*16);
      }
    }
    __syncthreads();

    bf16x8 af[WTM], bv[WTN];
#pragma unroll
    for (int mi=0; mi<WTM; mi++) {
      int row = wrow*(WTM*16) + mi*16 + l15;
      int sw  = quad ^ ((row >> 1) & 3);
      af[mi] = *(const bf16x8*)(As + row*64 + sw*16);
    }
#pragma unroll
    for (int nj=0; nj<WTN; nj++) {
      int rn = wcol*(WTN*16) + nj*16 + l15;
      int sw = quad ^ ((rn >> 1) & 3);
      bv[nj] = *(const bf16x8*)(Bs + rn*64 + sw*16);
    }
#pragma unroll
    for (int mi=0; mi<WTM; mi++)
#pragma unroll
      for (int nj=0; nj<WTN; nj++)
        acc[mi][nj] = MFMA16(af[mi], bv[nj], acc[mi][nj]);
  }
}

// ---------- double-buffered pipelined core (T3-minimum + T4 counted vmcnt) ----
// Per K-step: issue next-tile stage -> s_waitcnt vmcnt(LPT) (tile-k loads had a
// full iteration to land; the LPT just-issued loads stay IN FLIGHT across the
// barrier) -> s_barrier -> ds_read+MFMA -> s_barrier (arrival-only, no drain).
// This removes the per-iteration exposed vmcnt(0) drain of the old core
// (R12 counters: FFN1 602 TF == learn_hip m233's "2-phase stall" figure).
// Needs 2x LDS; used only by the big GEMM kernel (attention overlays keep core1).
template<int BM,int BN,int WROWS,int WCOLS,int WTM,int WTN>
__device__ __forceinline__ void gemm_bt_core2(
    const bf16_t* __restrict__ At, int lda,
    const bf16_t* __restrict__ Bt, int ldb,
    int Kd, char* sm, f32x4 (&acc)[WTM][WTN])
{
  constexpr int NT = WROWS*WCOLS*64;
  static_assert(WROWS*WTM*16 == BM && WCOLS*WTN*16 == BN, "tile mismatch");
  constexpr int HALF = (BM+BN)*64;
  const int t    = threadIdx.x;
  const int lane = t & 63;
  const int w    = t >> 6;
  const int wrow = w / WCOLS, wcol = w % WCOLS;
  const int l15  = lane & 15, quad = lane >> 4;

#pragma unroll
  for (int i=0;i<WTM;i++)
#pragma unroll
    for (int j=0;j<WTN;j++)
      acc[i][j] = f32x4{0.f,0.f,0.f,0.f};

  constexpr int CA = BM*4;
  static_assert(CA % NT == 0, "A staging must be whole issues");
  constexpr int AI    = CA / NT;
  constexpr int BFULL = (BN*4) / NT;
  static_assert((BN*4) % NT == 0, "core2 requires BREM==0");
  constexpr int LPT = AI + BFULL;   // vmem loads per thread per K-step
  static_assert(LPT == 3 || LPT == 4, "add vmcnt literal for this LPT");

  auto stage = [&](int kk, int buf) {
    char* As = sm + buf*HALF;
    char* Bs = As + BM*64;
#pragma unroll
    for (int ii=0; ii<AI; ii++) {
      int c  = ii*NT + t;
      int cw = ii*NT + (t & ~63);
      int r  = c >> 2;
      int js = (c & 3) ^ ((r >> 1) & 3);
      async_copy16(At + (size_t)r*lda + kk + js*8, As + (size_t)cw*16);
    }
#pragma unroll
    for (int ii=0; ii<BFULL; ii++) {
      int c  = ii*NT + t;
      int cw = ii*NT + (t & ~63);
      int r  = c >> 2;
      int js = (c & 3) ^ ((r >> 1) & 3);
      async_copy16(Bt + (size_t)r*ldb + kk + js*8, Bs + (size_t)cw*16);
    }
  };

  const int nk = Kd >> 5;
  stage(0, 0);
  for (int k = 0; k < nk; ++k) {
    const int cur = k & 1;
    if (k + 1 < nk) {
      stage((k+1) << 5, cur ^ 1);
      if constexpr (LPT == 3) asm volatile("s_waitcnt vmcnt(3)" ::: "memory");
      else                    asm volatile("s_waitcnt vmcnt(4)" ::: "memory");
    } else {
      asm volatile("s_waitcnt vmcnt(0)" ::: "memory");
    }
    __builtin_amdgcn_s_barrier();          // all waves' tile-k data landed
    asm volatile("" ::: "memory");

    char* As = sm + cur*HALF;
    char* Bs = As + BM*64;
    bf16x8 af[WTM], bv[WTN];
#pragma unroll
    for (int mi=0; mi<WTM; mi++) {
      int row = wrow*(WTM*16) + mi*16 + l15;
      int sw  = quad ^ ((row >> 1) & 3);
      af[mi] = *(const bf16x8*)(As + row*64 + sw*16);
    }
#pragma unroll
    for (int nj=0; nj<WTN; nj++) {
      int rn = wcol*(WTN*16) + nj*16 + l15;
      int sw = quad ^ ((rn >> 1) & 3);
      bv[nj] = *(const bf16x8*)(Bs + rn*64 + sw*16);
    }
#pragma unroll
    for (int mi=0; mi<WTM; mi++)
#pragma unroll
      for (int nj=0; nj<WTN; nj++)
        acc[mi][nj] = MFMA16(af[mi], bv[nj], acc[mi][nj]);

    asm volatile("" ::: "memory");
    __builtin_amdgcn_s_barrier();          // reads of buf[cur] done everywhere
  }
}

// ---------- epilogue variants ----------
enum { E_BF16 = 0, E_GELU = 2, E_RESF32 = 3, E_QKV = 5, E_F32 = 6 };

// exact-GELU via A&S 7.1.26 erf approximation (|err| ~1.5e-7).
__device__ __forceinline__ float gelu_f(float v) {
  float u  = v * 0.70710678118654752f;
  float au = fabsf(u);
  float tt = __builtin_amdgcn_rcpf(1.0f + 0.3275911f*au);
  float poly = tt*(0.254829592f + tt*(-0.284496736f + tt*(1.421413741f +
               tt*(-1.453152027f + tt*1.061405429f))));
  float er = 1.0f - poly*__expf(-au*au);
  er = __builtin_copysignf(er, u);
  return 0.5f * v * (1.0f + er);
}

template<int BM,int BN,int WROWS,int WCOLS,int WTM,int WTN,int EPI>
__global__ __launch_bounds__(WROWS*WCOLS*64)
void gemm_bt_kernel(const bf16_t* __restrict__ A, int lda,
                    const bf16_t* __restrict__ Bt, int ldb,
                    void* __restrict__ C, int ldc,
                    int Kd, const float* __restrict__ bias, const float* __restrict__ res)
{
  extern __shared__ float4 smem4[];
  char* sm = (char*)smem4;

  // XCD-aware bijective swizzle (T1): each XCD owns a contiguous work chunk.
  // E_F32 (split-K) uses a bx-MAJOR linearization so the blocks sharing one
  // A-panel (all by for a given bx) are adjacent in dispatch order -> A-panel
  // fetched ~once per XCD (R10: FETCH was 4.4x ideal with by-major order).
  const int nbx = gridDim.x;
  const int nwg = nbx * gridDim.y;
  int bx, by;
  {
    int orig;
    if constexpr (EPI == E_F32) orig = blockIdx.x * gridDim.y + blockIdx.y;
    else                        orig = blockIdx.y * nbx + blockIdx.x;
    if ((nwg & 7) == 0) {
      int swz = (orig & 7) * (nwg >> 3) + (orig >> 3);
      if constexpr (EPI == E_F32) { bx = swz / gridDim.y; by = swz % gridDim.y; }
      else                        { bx = swz % nbx;       by = swz / nbx; }
    } else { bx = blockIdx.x; by = blockIdx.y; }
  }

  // E_F32 = split-K=2 partials: upper half of by-range selects K-segment 1.
  int seg = 0;
  if constexpr (EPI == E_F32) {
    const int half = gridDim.y >> 1;
    if (by >= half) { seg = 1; by -= half; }
  }
  const int koff = seg * Kd;

  const bf16_t* At  = A  + (size_t)bx*BM*lda + koff;
  const bf16_t* Bt2 = Bt + (size_t)by*BN*ldb + koff;
  f32x4 acc[WTM][WTN];
  gemm_bt_core2<BM,BN,WROWS,WCOLS,WTM,WTN>(At, lda, Bt2, ldb, Kd, sm, acc);

  const int t=threadIdx.x, lane=t&63, w=t>>6;
  const int wrow=w/WCOLS, wcol=w%WCOLS, l15=lane&15, quad=lane>>4;

  if constexpr (EPI == E_QKV) {
    // merged QKV: by 0..7 -> q, 8..15 -> k, 16..23 -> vT (transposed)
    const int yb = by;
    bf16_t* base = (bf16_t*)C;              // qb; kb = +BSD; vT = +2*BSD
    if (yb < 16) {
      bf16_t* dst = base + (size_t)(yb >> 3) * BSDc;
      const size_t colbase = (size_t)(yb & 7) * 128;
#pragma unroll
      for (int mi=0; mi<WTM; mi++)
#pragma unroll
        for (int nj=0; nj<WTN; nj++) {
          size_t col = colbase + wcol*64 + nj*16 + l15;
#pragma unroll
          for (int reg=0; reg<4; reg++) {
            size_t row = (size_t)bx*128 + wrow*64 + mi*16 + quad*4 + reg;
            dst[row*D_ + col] = (bf16_t)acc[mi][nj][reg];
          }
        }
    } else {
      bf16_t* vT = base + 2*BSDc;
      bf16_t* ldsT = (bf16_t*)sm;           // [64 cols][136 rows]
      const int b  = (bx*128) >> 12;
      const int s0 = (bx*128) & 4095;
#pragma unroll
      for (int half2=0; half2<2; half2++) {
        __syncthreads();                    // core LDS reads done / prev drain done
        if (wcol == half2) {
#pragma unroll
          for (int mi=0; mi<WTM; mi++)
#pragma unroll
            for (int nj=0; nj<WTN; nj++)
#pragma unroll
              for (int reg=0; reg<4; reg++) {
                int col = nj*16 + l15;
                int row = wrow*64 + mi*16 + quad*4 + reg;
                ldsT[col*136 + row] = (bf16_t)acc[mi][nj][reg];
              }
        }
        __syncthreads();
        // 64 cols x 16 chunks = 1024 -> 4 passes
#pragma unroll
        for (int pass=0; pass<4; pass++) {
          int idx = pass*256 + t;
          int col = idx >> 4, ch = idx & 15;
          int d = (yb-16)*128 + half2*64 + col;
          int hh = d >> 6, cc = d & 63;
          bf16x8 v = *(const bf16x8*)(ldsT + col*136 + ch*8);
          *(bf16x8*)(vT + (((size_t)b*H_ + hh)*KH + cc)*S_ + s0 + ch*8) = v;
        }
      }
    }
    return;
  }

#pragma unroll
  for (int mi=0; mi<WTM; mi++) {
#pragma unroll
    for (int nj=0; nj<WTN; nj++) {
      size_t col = (size_t)by*BN + wcol*(WTN*16) + nj*16 + l15;
#pragma unroll
      for (int reg=0; reg<4; reg++) {
        size_t row = (size_t)bx*BM + wrow*(WTM*16) + mi*16 + quad*4 + reg;
        float v = acc[mi][nj][reg];
        if constexpr (EPI == E_BF16) {
          ((bf16_t*)C)[row*ldc + col] = (bf16_t)v;
        } else if constexpr (EPI == E_GELU) {
          v += bias[col];
          v = gelu_f(v);
          ((bf16_t*)C)[row*ldc + col] = (bf16_t)v;
        } else if constexpr (EPI == E_F32) {
          float* dst = (float*)C + (size_t)seg * ((size_t)gridDim.x * BM) * ldc;
          dst[row*ldc + col] = v;
        } else {  // E_RESF32
          if (bias) v += bias[col];
          v += res[row*(size_t)ldc + col];
          ((float*)C)[row*ldc + col] = v;
        }
      }
    }
  }
}

// ---------- fused phi(k) + kv aggregation ----------
// grid: (8 seg, 64 bh).  kvp fp32 [seg][bh][256 m][80 c]
__global__ __launch_bounds__(256)
void kv_fused(const bf16_t* __restrict__ kb, const float* __restrict__ sqk,
              const bf16_t* __restrict__ omg, const bf16_t* __restrict__ vT,
              float* __restrict__ kvp)
{
  extern __shared__ float4 smem4[];
  char* sm = (char*)smem4;
  bf16_t* PT   = (bf16_t*)sm;             // [256 m][72] (overlaps core As/Bs)
  bf16_t* Vs   = (bf16_t*)(sm + 36864);   // [80 c][64 s] (128B rows, 8 chunks, swizzled)
  float*  stab = (float*)(sm + 47104);    // 256
  float*  comb = (float*)(sm + 48128);    // 64
  const int g = blockIdx.x, bh = blockIdx.y, b = bh >> 4, h = bh & 15;
  const int t=threadIdx.x, lane=t&63, w=t>>6, l15=lane&15, quad=lane>>4;
  const float scale = 0.35355339059327379f;   // 64^-0.25

#pragma unroll
  for (int j=0;j<4;j++){
    int idx = j*256 + t;
    int r = 64 + (idx>>6), s = idx & 63;
    Vs[r*64 + s] = (bf16_t)((r==64) ? 1.0f : 0.0f);
  }

  f32x4 acc2[4][5];
#pragma unroll
  for (int i=0;i<4;i++)
#pragma unroll
    for (int j=0;j<5;j++) acc2[i][j] = f32x4{0.f,0.f,0.f,0.f};

  for (int ch=0; ch<8; ch++) {
    const int s0 = g*512 + ch*64;
    const bf16_t* At = kb + ((size_t)b*S_ + s0)*D_ + h*KH;
    f32x4 acc[4][4];
    gemm_bt_core<64,256,1,4,4,4>(At, D_, omg, KH, KH, sm, acc);

#pragma unroll
    for (int mi=0; mi<4; mi++) {
#pragma unroll
      for (int reg=0; reg<4; reg++) {
        float mx = fmaxf(fmaxf(acc[mi][0][reg], acc[mi][1][reg]),
                         fmaxf(acc[mi][2][reg], acc[mi][3][reg]));
#pragma unroll
        for (int off=1; off<16; off<<=1) mx = fmaxf(mx, __shfl_xor(mx, off, 64));
        if (l15 == 0) stab[w*64 + mi*16 + quad*4 + reg] = mx;
      }
    }
    __syncthreads();
    if (t < 64) {
      float m4 = fmaxf(fmaxf(stab[t], stab[64+t]), fmaxf(stab[128+t], stab[192+t]));
      comb[t] = m4*scale + sqk[(size_t)bh*S_ + s0 + t];
    }
    __syncthreads();
#pragma unroll
    for (int mi=0; mi<4; mi++)
#pragma unroll
      for (int nj=0; nj<4; nj++)
#pragma unroll
        for (int reg=0; reg<4; reg++) {
          int row = mi*16 + quad*4 + reg;          // s-local
          int col = w*64 + nj*16 + l15;            // m
          float p = __expf(scale*acc[mi][nj][reg] - comb[row]) * 0.0625f + 1e-6f;
          PT[col*72 + row] = (bf16_t)p;
        }
#pragma unroll
    for (int ii=0; ii<2; ii++) {
      int c2 = ii*256 + t;
      int cw = ii*256 + (t & ~63);
      int r  = c2 >> 3;
      int js = (c2 & 7) ^ (r & 7);
      async_copy16(vT + ((size_t)bh*KH + r)*S_ + s0 + js*8,
                   (char*)Vs + (size_t)cw*16);
    }
    __syncthreads();
#pragma unroll
    for (int ks=0; ks<2; ks++) {
      bf16x8 af[4];
#pragma unroll
      for (int mi=0; mi<4; mi++)
        af[mi] = *(const bf16x8*)(PT + (w*64 + mi*16 + l15)*72 + ks*32 + quad*8);
#pragma unroll
      for (int nj=0; nj<5; nj++) {
        int rr = nj*16 + l15;
        int slot = (ks*4 + quad) ^ (rr & 7);
        bf16x8 bv = *(const bf16x8*)(Vs + rr*64 + slot*8);
#pragma unroll
        for (int mi=0; mi<4; mi++)
          acc2[mi][nj] = MFMA16(af[mi], bv, acc2[mi][nj]);
      }
    }
  }

#pragma unroll
  for (int mi=0; mi<4; mi++)
#pragma unroll
    for (int nj=0; nj<5; nj++)
#pragma unroll
      for (int reg=0; reg<4; reg++) {
        int m = w*64 + mi*16 + quad*4 + reg;
        int c = nj*16 + l15;
        kvp[(((size_t)g*64 + bh)*256 + m)*80 + c] = acc2[mi][nj][reg];
      }
}

// reduce 8 segments -> kvT[bh][c][m] fp16; grid (4 mblk, 64 bh)
__global__ __launch_bounds__(256)
void kvred_kernel(const float* __restrict__ kvp, bf16_t* __restrict__ kvT)
{
  __shared__ float accs[64*81];
  const int mb = blockIdx.x, bh = blockIdx.y, t = threadIdx.x;
  const int m0 = mb*64;
  float r[20];
#pragma unroll
  for (int i=0;i<20;i++) r[i] = 0.f;
  for (int g2=0; g2<8; g2++) {
    const float* p = kvp + (((size_t)g2*64 + bh)*256 + m0)*80;
#pragma unroll
    for (int i=0;i<20;i++) r[i] += p[i*256 + t];
  }
#pragma unroll
  for (int i=0;i<20;i++) {
    int idx = i*256 + t;           // = mloc*80 + c
    int ml = idx / 80, cc = idx - ml*80;
    accs[ml*81 + cc] = r[i];
  }
  __syncthreads();
  bf16_t* o = kvT + (size_t)bh*(80*M_);
#pragma unroll
  for (int i=0;i<20;i++) {
    int idx2 = i*256 + t;          // = c*64 + mloc
    int c = idx2 >> 6, ml = idx2 & 63;
    o[(size_t)c*M_ + m0 + ml] = (bf16_t)accs[ml*81 + c];
  }
}

// ---------- fused phi(q) + num/den ----------
__global__ __launch_bounds__(256)
void numden_fused(const bf16_t* __restrict__ qb, const float* __restrict__ sqv,
                  const bf16_t* __restrict__ omg, const bf16_t* __restrict__ kvT,
                  bf16_t* __restrict__ attn)
{
  extern __shared__ float4 smem4[];
  char* sm = (char*)smem4;
  bf16_t* P    = (bf16_t*)sm;             // [64 s][264 m] (overlaps core As/Bs)
  char*   Bs2  = sm + 33792;              // 80 rows x 64B (4 chunks, swizzled)
  float*  stab = (float*)(sm + 38912);
  float*  comb = (float*)(sm + 39936);
  const int bh = blockIdx.y, b = bh >> 4, h = bh & 15;
  const int s0 = blockIdx.x * 64;
  const bf16_t* At = qb + ((size_t)b*S_ + s0)*D_ + h*KH;
  f32x4 acc[4][4];
  gemm_bt_core<64,256,1,4,4,4>(At, D_, omg, KH, KH, sm, acc);

  const int t=threadIdx.x, lane=t&63, w=t>>6, l15=lane&15, quad=lane>>4;
  const float scale = 0.35355339059327379f;

#pragma unroll
  for (int mi=0; mi<4; mi++) {
#pragma unroll
    for (int reg=0; reg<4; reg++) {
      float mx = fmaxf(fmaxf(acc[mi][0][reg], acc[mi][1][reg]),
                       fmaxf(acc[mi][2][reg], acc[mi][3][reg]));
#pragma unroll
      for (int off=1; off<16; off<<=1) mx = fmaxf(mx, __shfl_xor(mx, off, 64));
      if (l15 == 0) stab[w*64 + mi*16 + quad*4 + reg] = mx;
    }
  }
  __syncthreads();
  if (t < 64) {
    float m4 = fmaxf(fmaxf(stab[t], stab[64+t]), fmaxf(stab[128+t], stab[192+t]));
    comb[t] = m4*scale + sqv[(size_t)bh*S_ + s0 + t];
  }
  __syncthreads();
#pragma unroll
  for (int mi=0; mi<4; mi++)
#pragma unroll
    for (int nj=0; nj<4; nj++)
#pragma unroll
      for (int reg=0; reg<4; reg++) {
        int row = mi*16 + quad*4 + reg;
        int col = w*64 + nj*16 + l15;
        float p = __expf(scale*acc[mi][nj][reg] - comb[row]) * 0.0625f + 1e-6f;
        P[row*264 + col] = (bf16_t)p;
      }

  const bf16_t* Bt = kvT + (size_t)bh*80*M_;
  f32x4 acc2[5];
#pragma unroll
  for (int j=0;j<5;j++) acc2[j] = f32x4{0.f,0.f,0.f,0.f};

  for (int kk = 0; kk < 256; kk += 32) {
    __syncthreads();
    {
      int c = t, cw = (t & ~63);
      int r = c >> 2;
      int js = (c & 3) ^ ((r >> 1) & 3);
      async_copy16(Bt + (size_t)r*M_ + kk + js*8, Bs2 + (size_t)cw*16);
    }
    if (t < 64) {
      int c = 256 + t;
      int r = c >> 2;
      int js = (c & 3) ^ ((r >> 1) & 3);
      async_copy16(Bt + (size_t)r*M_ + kk + js*8, Bs2 + (size_t)256*16);
    }
    __syncthreads();
    bf16x8 af = *(const bf16x8*)(P + (w*16 + l15)*264 + kk + quad*8);
#pragma unroll
    for (int nj=0; nj<5; nj++) {
      int rn = nj*16 + l15;
      int sw = quad ^ ((rn >> 1) & 3);
      bf16x8 bv = *(const bf16x8*)(Bs2 + rn*64 + sw*16);
      acc2[nj] = MFMA16(af, bv, acc2[nj]);
    }
  }

#pragma unroll
  for (int reg=0; reg<4; reg++) {
    float den = __shfl(acc2[4][reg], (lane & 48), 64);
    int row = w*16 + quad*4 + reg;
#pragma unroll
    for (int nj=0; nj<4; nj++) {
      float v = acc2[nj][reg] / den;
      attn[((size_t)b*S_ + s0 + row)*D_ + h*KH + nj*16 + l15] = (bf16_t)v;
    }
  }
}

// ---------- small kernels ----------
__global__ __launch_bounds__(256)
void cvt_kernel(const float* __restrict__ in, bf16_t* __restrict__ out)
{
  const size_t i = ((size_t)blockIdx.x*256 + threadIdx.x)*4;
  const float4 a = *(const float4*)(in + i);
  bf16x4 o; o[0]=(bf16_t)a.x; o[1]=(bf16_t)a.y; o[2]=(bf16_t)a.z; o[3]=(bf16_t)a.w;
  *(bf16x4*)(out + i) = o;
}

__global__ __launch_bounds__(256)
void tcvt_kernel(const float* __restrict__ in, bf16_t* __restrict__ out, int R, int C)
{
  __shared__ float tile[64][65];
  const int r0 = blockIdx.y*64, c0 = blockIdx.x*64;
  const int tx = threadIdx.x & 63, ty = threadIdx.x >> 6;
  for (int i=ty; i<64; i+=4) tile[i][tx] = in[(size_t)(r0+i)*C + c0 + tx];
  __syncthreads();
  for (int i=ty; i<64; i+=4) out[(size_t)(c0+i)*R + r0 + tx] = (bf16_t)tile[tx][i];
}

// merged wq/wk/wv transpose (1024x1024 each) -> stacked wqkvT; grid (16, 48)
__global__ __launch_bounds__(256)
void tcvt3_kernel(const float* __restrict__ wqp, const float* __restrict__ wkp,
                  const float* __restrict__ wvp, bf16_t* __restrict__ out)
{
  __shared__ float tile[64][65];
  const int sel = blockIdx.y >> 4, ry = blockIdx.y & 15;
  const float* in = (sel==0) ? wqp : (sel==1) ? wkp : wvp;
  bf16_t* o = out + (size_t)sel*D_*D_;
  const int r0 = ry*64, c0 = blockIdx.x*64;
  const int tx = threadIdx.x & 63, ty = threadIdx.x >> 6;
  for (int i=ty; i<64; i+=4) tile[i][tx] = in[(size_t)(r0+i)*D_ + c0 + tx];
  __syncthreads();
  for (int i=ty; i<64; i+=4) o[(size_t)(c0+i)*D_ + r0 + tx] = (bf16_t)tile[tx][i];
}

// merged sq for q and k: blocks 0..4095 -> qb rows, 4096..8191 -> kb rows
__global__ __launch_bounds__(256)
void sq2_kernel(const bf16_t* __restrict__ qkv, float* __restrict__ sqq,
                float* __restrict__ sqk)
{
  const int bi   = blockIdx.x;
  const int ksel = bi >> 12;
  const int i    = ((bi & 4095)<<2) + (threadIdx.x>>6);
  const int lane = threadIdx.x & 63;
  const bf16_t* row = qkv + (size_t)ksel*BSDc + (size_t)i*D_ + lane*16;
  bf16x8 v0 = *(const bf16x8*)row;
  bf16x8 v1 = *(const bf16x8*)(row + 8);
  float s = 0.f;
#pragma unroll
  for (int j=0;j<8;j++){ float a=(float)v0[j], c=(float)v1[j]; s += a*a + c*c; }
  s += __shfl_xor(s, 1, 64);
  s += __shfl_xor(s, 2, 64);
  if ((lane&3)==0) {
    const int h = lane>>2, b = i>>12, ss = i & 4095;
    float* sq = ksel ? sqk : sqq;
    sq[((size_t)b*H_ + h)*S_ + ss] = 0.0625f * s;
  }
}

// fused split-K reduce + residual + LN1 + fp16 copy; one block per row.
__global__ __launch_bounds__(256)
void ln1red_kernel(const float* __restrict__ p2, const float* __restrict__ res,
                   const float* __restrict__ g, const float* __restrict__ bt,
                   float* __restrict__ outf, bf16_t* __restrict__ outb)
{
  __shared__ float rs[4], rs2[4];
  const size_t row = blockIdx.x;
  const int t = threadIdx.x;
  const float4 a0 = ((const float4*)(p2 + row*D_))[t];
  const float4 a1 = ((const float4*)(p2 + BSDc + row*D_))[t];
  const float4 rr = ((const float4*)(res + row*D_))[t];
  float4 a;
  a.x = a0.x + a1.x + rr.x;
  a.y = a0.y + a1.y + rr.y;
  a.z = a0.z + a1.z + rr.z;
  a.w = a0.w + a1.w + rr.w;
  float s  = a.x+a.y+a.z+a.w;
  float s2 = a.x*a.x + a.y*a.y + a.z*a.z + a.w*a.w;
#pragma unroll
  for (int off=32; off; off>>=1) { s += __shfl_xor(s, off, 64); s2 += __shfl_xor(s2, off, 64); }
  if ((t&63)==0) { rs[t>>6]=s; rs2[t>>6]=s2; }
  __syncthreads();
  const float S1 = rs[0]+rs[1]+rs[2]+rs[3];
  const float S2 = rs2[0]+rs2[1]+rs2[2]+rs2[3];
  const float mu   = S1 * (1.f/1024.f);
  const float rstd = rsqrtf(S2 * (1.f/1024.f) - mu*mu + 1e-6f);
  const float4 gg = ((const float4*)g)[t];
  const float4 bb = ((const float4*)bt)[t];
  float4 oo;
  oo.x = (a.x-mu)*rstd*gg.x + bb.x;
  oo.y = (a.y-mu)*rstd*gg.y + bb.y;
  oo.z = (a.z-mu)*rstd*gg.z + bb.z;
  oo.w = (a.w-mu)*rstd*gg.w + bb.w;
  ((float4*)(outf + row*D_))[t] = oo;
  bf16x4 ob; ob[0]=(bf16_t)oo.x; ob[1]=(bf16_t)oo.y; ob[2]=(bf16_t)oo.z; ob[3]=(bf16_t)oo.w;
  *(bf16x4*)(outb + row*D_ + t*4) = ob;
}

// fused split-K reduce + bias + residual + LN2; one block per row.
__global__ __launch_bounds__(256)
void ln2red_kernel(const float* __restrict__ p2, const float* __restrict__ bias,
                   const float* __restrict__ res, const float* __restrict__ g,
                   const float* __restrict__ bt, float* __restrict__ outp)
{
  __shared__ float rs[4], rs2[4];
  const size_t row = blockIdx.x;
  const int t = threadIdx.x;
  const float4 a0 = ((const float4*)(p2 + row*D_))[t];
  const float4 a1 = ((const float4*)(p2 + BSDc + row*D_))[t];
  const float4 bb2 = ((const float4*)bias)[t];
  const float4 rr = ((const float4*)(res + row*D_))[t];
  float4 a;
  a.x = a0.x + a1.x + bb2.x + rr.x;
  a.y = a0.y + a1.y + bb2.y + rr.y;
  a.z = a0.z + a1.z + bb2.z + rr.z;
  a.w = a0.w + a1.w + bb2.w + rr.w;
  float s  = a.x+a.y+a.z+a.w;
  float s2 = a.x*a.x + a.y*a.y + a.z*a.z + a.w*a.w;
#pragma unroll
  for (int off=32; off; off>>=1) { s += __shfl_xor(s, off, 64); s2 += __shfl_xor(s2, off, 64); }
  if ((t&63)==0) { rs[t>>6]=s; rs2[t>>6]=s2; }
  __syncthreads();
  const float S1 = rs[0]+rs[1]+rs[2]+rs[3];
  const float S2 = rs2[0]+rs2[1]+rs2[2]+rs2[3];
  const float mu   = S1 * (1.f/1024.f);
  const float rstd = rsqrtf(S2 * (1.f/1024.f) - mu*mu + 1e-6f);
  const float4 gg = ((const float4*)g)[t];
  const float4 bb = ((const float4*)bt)[t];
  float4 oo;
  oo.x = (a.x-mu)*rstd*gg.x + bb.x;
  oo.y = (a.y-mu)*rstd*gg.y + bb.y;
  oo.z = (a.z-mu)*rstd*gg.z + bb.z;
  oo.w = (a.w-mu)*rstd*gg.w + bb.w;
  ((float4*)(outp + row*D_))[t] = oo;
}

// ---------- load-time fallback workspace ----------
// Alloc-list sum = 474.5 MB; 480 MB gives headroom + alignment pad.
static const size_t NEED = 480000000;
static void* g_fb = nullptr;
struct FbInit {
  FbInit() { if (hipMalloc(&g_fb, NEED) != hipSuccess) g_fb = nullptr; }
};
static FbInit g_fbinit;

// ---------- launcher ----------
extern "C" void kernel_launch(void* const* d_in, const int* in_sizes, int n_in,
                              void* d_out, int out_size, void* d_ws, size_t ws_size,
                              hipStream_t stream)
{
  (void)in_sizes; (void)n_in; (void)out_size;
  const float* x     = (const float*)d_in[0];
  const float* wq    = (const float*)d_in[1];
  const float* wk    = (const float*)d_in[2];
  const float* wv    = (const float*)d_in[3];
  const float* wo    = (const float*)d_in[4];
  const float* omega = (const float*)d_in[5];
  const float* ln1g  = (const float*)d_in[6];
  const float* ln1b  = (const float*)d_in[7];
  const float* w1    = (const float*)d_in[8];
  const float* b1    = (const float*)d_in[9];
  const float* w2    = (const float*)d_in[10];
  const float* b2    = (const float*)d_in[11];
  const float* ln2g  = (const float*)d_in[12];
  const float* ln2b  = (const float*)d_in[13];
  float* out = (float*)d_out;

  char* ws = (ws_size >= NEED) ? (char*)d_ws : (char*)g_fb;
  if (!ws) return;

  size_t o = 0;
  auto alloc = [&](size_t bytes) -> char* {
    char* p = ws + o; o += (bytes + 255) & ~(size_t)255; return p;
  };
  const size_t BSD = BSDc;

  bf16_t* wqkvT = (bf16_t*)alloc((size_t)3*D_*D_*2);      // stacked q|k|v B^T
  bf16_t* woT   = (bf16_t*)alloc((size_t)D_*D_*2);
  bf16_t* w1T   = (bf16_t*)alloc((size_t)D_*FF_*2);
  bf16_t* w2T   = (bf16_t*)alloc((size_t)D_*FF_*2);
  bf16_t* omg   = (bf16_t*)alloc((size_t)M_*KH*2);
  float*  sqq   = (float*)alloc((size_t)B_*H_*S_*4);
  float*  sqk   = (float*)alloc((size_t)B_*H_*S_*4);
  bf16_t* kvT   = (bf16_t*)alloc((size_t)B_*H_*80*M_*2);
  float*  kvp   = (float*)alloc((size_t)8*64*256*80*4);   // 42 MB

  bf16_t* xb    = (bf16_t*)alloc(BSD*2);                  // -> x1b
  bf16_t* qkv   = (bf16_t*)alloc(3*BSD*2);                // qb | kb | vT contiguous
  bf16_t* h1    = (bf16_t*)alloc(BSD*4*2);                // 128 MB fp16 [16384][4096]
  float*  p2    = (float*)alloc(2*BSD*4);                 // 128 MB fp32 split-K partials

  bf16_t* x1b  = xb;
  bf16_t* qb   = qkv;
  bf16_t* kb   = qkv + BSD;
  bf16_t* vT   = qkv + 2*BSD;
  bf16_t* attn = qb;              // in-place over qb
  float*  y1   = (float*)d_out;   // fp32 x1 (LN1 out) lives in d_out until LN2

  constexpr int SH128 = (128+128)*64*2;    // 32768 (double-buffered core2)
  constexpr int SHQKV = 32768;             // >= max(core2 32768, transpose 17408)
  constexpr int SHFF  = (128+256)*64*2;    // 49152 (128x256 tile, dbuf)
  constexpr int SHKF  = 48384;
  constexpr int SHND  = 40192;

  // 1. converts / weight transposes
  cvt_kernel<<<(int)(BSD/1024), 256, 0, stream>>>(x, xb);
  tcvt3_kernel<<<dim3(16,48), 256, 0, stream>>>(wq, wk, wv, wqkvT);
  tcvt_kernel<<<dim3(16,16), 256, 0, stream>>>(wo, woT, 1024, 1024);
  tcvt_kernel<<<dim3(64,16), 256, 0, stream>>>(w1, w1T, 1024, 4096);
  tcvt_kernel<<<dim3(16,64), 256, 0, stream>>>(w2, w2T, 4096, 1024);
  cvt_kernel<<<16, 256, 0, stream>>>(omega, omg);

  // 2. merged QKV projection: [16384,1024] x [3072,1024]^T, 3072 blocks
  gemm_bt_kernel<128,128,2,2,4,4,E_QKV><<<dim3(128,24), 256, SHQKV, stream>>>(
      xb, D_, wqkvT, D_, qkv, D_, D_, nullptr, nullptr);

  // 3. sq (merged q+k)
  sq2_kernel<<<8192, 256, 0, stream>>>(qkv, sqq, sqk);

  // 4. fused phi(k)+kv aggregation (8 segments = 512 blocks), then reduce
  kv_fused<<<dim3(8,64), 256, SHKF, stream>>>(kb, sqk, omg, vT, kvp);
  kvred_kernel<<<dim3(4,64), 256, 0, stream>>>(kvp, kvT);

  // 5. fused phi(q)+num/den -> attn (in place over qb)
  numden_fused<<<dim3(64,64), 256, SHND, stream>>>(qb, sqq, omg, kvT, attn);

  // 6. out projection split-K=2 (2048 blocks, K=512/seg -> p2 partials),
  //    then fused reduce + residual(x) + LN1 -> y1 fp32 + x1b fp16
  gemm_bt_kernel<128,128,2,2,4,4,E_F32><<<dim3(128,16), 256, SH128, stream>>>(
      attn, D_, woT, D_, p2, D_, 512, nullptr, nullptr);
  ln1red_kernel<<<B_*S_, 256, 0, stream>>>(p2, x, ln1g, ln1b, y1, x1b);

  // 7. FFN1 128x256 tile / 8 waves (2048 blocks);
  //    FFN2 128x256 tile split-K=2 (1024 blocks, K=2048/seg, bx-major order)
  gemm_bt_kernel<128,256,2,4,4,4,E_GELU><<<dim3(128,16), 512, SHFF, stream>>>(
      x1b, D_, w1T, D_, h1, FF_, D_, b1, nullptr);
  gemm_bt_kernel<128,256,2,4,4,4,E_F32><<<dim3(128,8), 512, SHFF, stream>>>(
      h1, FF_, w2T, FF_, p2, D_, 2048, nullptr, nullptr);

  // 8. fused reduce + b2 + residual(y1) + LN2 -> output
  ln2red_kernel<<<B_*S_, 256, 0, stream>>>(p2, b2, y1, ln2g, ln2b, out);
}